// Round 1
// baseline (3179.240 us; speedup 1.0000x reference)
//
#include <hip/hip_runtime.h>
#include <math.h>

#define Bn   4
#define CINc 64
#define Hh   160
#define Ww   160
#define Gg   8
#define CGc  8
#define HW   (Hh * Ww)      // 25600
#define COFF 216            // 3*G*KK

// ---------------- Kernel 1: 3x3 offset conv (feat -> ws[4,216,160,160]) ----
#define K1_TW 16
#define K1_TH 8
#define K1_THREADS 128
#define K1_COB 24           // 216 / 24 = 9 chunks

__global__ __launch_bounds__(K1_THREADS)
void offset_conv_kernel(const float* __restrict__ feat,
                        const float* __restrict__ w_off,
                        const float* __restrict__ b_off,
                        float* __restrict__ ws) {
    __shared__ float ftile[CINc * 10 * 18];   // 46080 B: [ci][ry(10)][rx(18)]
    const int b  = blockIdx.z;
    const int h0 = blockIdx.y * K1_TH;
    const int w0 = blockIdx.x * K1_TW;
    const int t  = threadIdx.x;

    // Stage input halo tile (zero-padded)
    for (int e = t; e < CINc * 180; e += K1_THREADS) {
        int ci = e / 180;
        int r  = e % 180;
        int ry = r / 18;
        int rx = r % 18;
        int gh = h0 - 1 + ry;
        int gw = w0 - 1 + rx;
        float v = 0.f;
        if (gh >= 0 && gh < Hh && gw >= 0 && gw < Ww)
            v = feat[(((size_t)b * CINc + ci) * Hh + gh) * Ww + gw];
        ftile[e] = v;
    }
    __syncthreads();

    const int py = t / K1_TW;   // [0,8)
    const int px = t % K1_TW;   // [0,16)
    const int h = h0 + py, w = w0 + px;

    for (int cc = 0; cc < COFF / K1_COB; ++cc) {
        const int co0 = cc * K1_COB;
        float acc[K1_COB];
        #pragma unroll
        for (int i = 0; i < K1_COB; ++i) acc[i] = 0.f;

        for (int ci = 0; ci < CINc; ++ci) {
            #pragma unroll
            for (int ky = 0; ky < 3; ++ky) {
                const int rowbase = ci * 180 + (py + ky) * 18 + px;
                #pragma unroll
                for (int kx = 0; kx < 3; ++kx) {
                    const float v = ftile[rowbase + kx];
                    const int ck = ci * 9 + ky * 3 + kx;
                    #pragma unroll
                    for (int i = 0; i < K1_COB; ++i)
                        acc[i] += v * w_off[(size_t)(co0 + i) * 576 + ck];
                }
            }
        }
        #pragma unroll
        for (int i = 0; i < K1_COB; ++i)
            ws[(((size_t)b * COFF + co0 + i) * Hh + h) * Ww + w] = acc[i] + b_off[co0 + i];
    }
}

// ---------------- Kernel 2: modulated deformable conv ----------------------
#define K2_TW 8
#define K2_TH 4
#define TPIX 32
#define K2_THREADS 256
#define WPAD 68   // wbuf row stride (floats), 16B-aligned rows

__global__ __launch_bounds__(K2_THREADS)
void dcn_kernel(const float* __restrict__ x,
                const float* __restrict__ ws,
                const float* __restrict__ w_dcn,
                const float* __restrict__ b_dcn,
                float* __restrict__ out) {
    __shared__ float vbuf[72 * TPIX];    // [cg*9+k][pix]   9216 B
    __shared__ float wbuf[72 * WPAD];    // [ck][o] (transposed w slice) 19584 B

    const int b  = blockIdx.z;
    const int h0 = blockIdx.y * K2_TH;
    const int w0 = blockIdx.x * K2_TW;
    const int t  = threadIdx.x;
    const int pix2 = t & 15;     // pixel pair index
    const int ob   = t >> 4;     // [0,16)
    const int o0   = ob * 4;

    float acc[4][2];
    #pragma unroll
    for (int i = 0; i < 4; ++i) { acc[i][0] = 0.f; acc[i][1] = 0.f; }

    for (int g = 0; g < Gg; ++g) {
        // Stage weight slice transposed: wbuf[ck][o] = w_dcn[o][g*8 + ck/9][ck%9]
        for (int e = t; e < 64 * 72; e += K2_THREADS) {
            int o  = e / 72;
            int ck = e % 72;
            wbuf[ck * WPAD + o] = w_dcn[(size_t)o * 576 + g * 72 + ck];
        }
        // Phase 1: bilinear sampling into vbuf
        for (int task = t; task < 288; task += K2_THREADS) {
            const int pix = task & 31;
            const int k   = task >> 5;         // [0,9)
            const int h = h0 + (pix >> 3);
            const int w = w0 + (pix & 7);
            const size_t obase = (((size_t)b * COFF + g * 18 + k * 2) * Hh + h) * Ww + w;
            const float dy = ws[obase];
            const float dx = ws[obase + HW];
            const float m  = ws[(((size_t)b * COFF + 144 + g * 9 + k) * Hh + h) * Ww + w];
            const float mask = 1.f / (1.f + expf(-m));

            const float py  = (float)h + (float)(k / 3 - 1) + dy;
            const float pxx = (float)w + (float)(k % 3 - 1) + dx;
            const float y0f = floorf(py), x0f = floorf(pxx);
            const float ly = py - y0f, lx = pxx - x0f;
            const int y0 = (int)y0f, x0i = (int)x0f;
            const int y1 = y0 + 1,  x1  = x0i + 1;

            const float vy0 = (y0 >= 0 && y0 < Hh) ? 1.f : 0.f;
            const float vy1 = (y1 >= 0 && y1 < Hh) ? 1.f : 0.f;
            const float vx0 = (x0i >= 0 && x0i < Ww) ? 1.f : 0.f;
            const float vx1 = (x1 >= 0 && x1 < Ww) ? 1.f : 0.f;

            const float c00 = (1.f - ly) * (1.f - lx) * vy0 * vx0 * mask;
            const float c01 = (1.f - ly) * lx         * vy0 * vx1 * mask;
            const float c10 = ly         * (1.f - lx) * vy1 * vx0 * mask;
            const float c11 = ly         * lx         * vy1 * vx1 * mask;

            const int y0c = min(max(y0, 0), Hh - 1), y1c = min(max(y1, 0), Hh - 1);
            const int x0c = min(max(x0i, 0), Ww - 1), x1c = min(max(x1, 0), Ww - 1);
            const int i00 = y0c * Ww + x0c, i01 = y0c * Ww + x1c;
            const int i10 = y1c * Ww + x0c, i11 = y1c * Ww + x1c;

            const float* xb = x + ((size_t)b * CINc + g * CGc) * HW;
            #pragma unroll
            for (int cg = 0; cg < CGc; ++cg) {
                const float* xc = xb + cg * HW;
                const float v = c00 * xc[i00] + c01 * xc[i01]
                              + c10 * xc[i10] + c11 * xc[i11];
                vbuf[(cg * 9 + k) * TPIX + pix] = v;
            }
        }
        __syncthreads();

        // Phase 2: out[o, pix] += sum_ck wbuf[ck][o] * vbuf[ck][pix]
        for (int ck = 0; ck < 72; ++ck) {
            const float4 wv = *(const float4*)&wbuf[ck * WPAD + o0];
            const float2 vv = *(const float2*)&vbuf[ck * TPIX + pix2 * 2];
            acc[0][0] += wv.x * vv.x; acc[0][1] += wv.x * vv.y;
            acc[1][0] += wv.y * vv.x; acc[1][1] += wv.y * vv.y;
            acc[2][0] += wv.z * vv.x; acc[2][1] += wv.z * vv.y;
            acc[3][0] += wv.w * vv.x; acc[3][1] += wv.w * vv.y;
        }
        __syncthreads();
    }

    // Epilogue
    #pragma unroll
    for (int i = 0; i < 4; ++i) {
        const float bias = b_dcn[o0 + i];
        #pragma unroll
        for (int j = 0; j < 2; ++j) {
            const int pix = pix2 * 2 + j;
            const int h = h0 + (pix >> 3);
            const int w = w0 + (pix & 7);
            out[(((size_t)b * CINc + o0 + i) * Hh + h) * Ww + w] = acc[i][j] + bias;
        }
    }
}

extern "C" void kernel_launch(void* const* d_in, const int* in_sizes, int n_in,
                              void* d_out, int out_size, void* d_ws, size_t ws_size,
                              hipStream_t stream) {
    const float* x     = (const float*)d_in[0];
    const float* feat  = (const float*)d_in[1];
    const float* w_off = (const float*)d_in[2];
    const float* b_off = (const float*)d_in[3];
    const float* w_dcn = (const float*)d_in[4];
    const float* b_dcn = (const float*)d_in[5];
    float* out   = (float*)d_out;
    float* wsbuf = (float*)d_ws;     // needs 4*216*160*160*4 = 88.5 MB

    offset_conv_kernel<<<dim3(Ww / K1_TW, Hh / K1_TH, Bn), K1_THREADS, 0, stream>>>(
        feat, w_off, b_off, wsbuf);
    dcn_kernel<<<dim3(Ww / K2_TW, Hh / K2_TH, Bn), K2_THREADS, 0, stream>>>(
        x, wsbuf, w_dcn, b_dcn, out);
}

// Round 2
// 381.345 us; speedup vs baseline: 8.3369x; 8.3369x over previous
//
#include <hip/hip_runtime.h>
#include <math.h>

#define Bn   4
#define CINc 64
#define Hh   160
#define Ww   160
#define Gg   8
#define CGc  8
#define HW   (Hh * Ww)      // 25600
#define COFF 216            // 3*G*KK
#define MPAD 224            // 216 padded to 14*16

typedef short bf16x8 __attribute__((ext_vector_type(8)));
typedef float f32x4  __attribute__((ext_vector_type(4)));

static __device__ __forceinline__ unsigned short f2bf(float f) {
    unsigned int u = __float_as_uint(f);
    u = (u + 0x7fffu + ((u >> 16) & 1u)) >> 16;
    return (unsigned short)u;
}
static __device__ __forceinline__ float bf2f(unsigned short s) {
    return __uint_as_float(((unsigned int)s) << 16);
}
static __device__ __forceinline__ float blo(unsigned int u) {
    return __uint_as_float(u << 16);
}
static __device__ __forceinline__ float bhi(unsigned int u) {
    return __uint_as_float(u & 0xffff0000u);
}

// ---------- Prep 1: NCHW fp32 -> NHWC bf16 for feat and x -------------------
__global__ __launch_bounds__(256)
void nchw_to_nhwc_bf16(const float* __restrict__ feat, const float* __restrict__ x,
                       unsigned short* __restrict__ featT, unsigned short* __restrict__ xT) {
    __shared__ float tile[CINc][161];   // pad 161: conflict-free transpose
    const int h = blockIdx.x;
    const int b = blockIdx.y;
    const float* src = blockIdx.z ? x : feat;
    unsigned short* dst = blockIdx.z ? xT : featT;
    const int t = threadIdx.x;
    for (int i = t; i < CINc * Ww; i += 256) {
        int ci = i / Ww, w = i % Ww;
        tile[ci][w] = src[(((size_t)b * CINc + ci) * Hh + h) * Ww + w];
    }
    __syncthreads();
    for (int i = t; i < CINc * Ww; i += 256) {
        int w = i / CINc, ci = i % CINc;
        dst[(((size_t)b * Hh + h) * Ww + w) * CINc + ci] = f2bf(tile[ci][w]);
    }
}

// ---------- Prep 2: w_off [216][64][3][3] fp32 -> [9][224][64] bf16 ---------
__global__ __launch_bounds__(256)
void woff_repack(const float* __restrict__ w_off, unsigned short* __restrict__ wbf) {
    const int e = blockIdx.x * 256 + threadIdx.x;   // 9*224*64 = 129024
    if (e >= 9 * MPAD * CINc) return;
    const int kp = e / (MPAD * CINc);
    const int r  = e % (MPAD * CINc);
    const int co = r >> 6;
    const int ci = r & 63;
    float v = (co < COFF) ? w_off[(size_t)co * 576 + ci * 9 + kp] : 0.f;
    wbf[e] = f2bf(v);
}

// ---------- Kernel 1: 3x3 conv as implicit-GEMM MFMA -----------------------
// block: 256 thr (4 waves), pixel tile 16x8, M=224 (14 tiles), K=576
__global__ __launch_bounds__(256, 2)
void offset_conv_mfma(const unsigned short* __restrict__ featT,
                      const unsigned short* __restrict__ wbf,
                      const float* __restrict__ b_off,
                      unsigned short* __restrict__ conv_out) {
    __shared__ unsigned short halo[10 * 18 * 72];   // [ry][rx][ci pad 72] 25920 B
    __shared__ unsigned short wtile[MPAD * 72];     // [co][ci pad 72]     32256 B

    const int b  = blockIdx.z;
    const int h0 = blockIdx.y * 8;
    const int w0 = blockIdx.x * 16;
    const int t  = threadIdx.x;

    // stage halo: 180 pixels x 8 chunks of 8 bf16 (16 B)
    for (int task = t; task < 1440; task += 256) {
        const int pix = task >> 3, ch = task & 7;
        const int ry = pix / 18, rx = pix % 18;
        const int gh = h0 - 1 + ry, gw = w0 - 1 + rx;
        float4 v = make_float4(0.f, 0.f, 0.f, 0.f);
        if (gh >= 0 && gh < Hh && gw >= 0 && gw < Ww)
            v = *(const float4*)(featT + ((((size_t)b * Hh) + gh) * Ww + gw) * CINc + ch * 8);
        *(float4*)(halo + pix * 72 + ch * 8) = v;
    }

    f32x4 acc[14][2] = {};
    const int wv   = t >> 6;
    const int lane = t & 63;
    const int n    = lane & 15;     // pixel / co-row selector
    const int kg   = lane >> 4;     // k-group
    const int py0  = wv * 2;

    for (int kp = 0; kp < 9; ++kp) {
        __syncthreads();   // protects wtile (and halo on first iter)
        for (int task = t; task < 1792; task += 256) {
            const int row = task >> 3, ch = task & 7;
            *(float4*)(wtile + row * 72 + ch * 8) =
                *(const float4*)(wbf + ((size_t)kp * MPAD + row) * CINc + ch * 8);
        }
        __syncthreads();
        const int ky = kp / 3, kx = kp % 3;
        #pragma unroll
        for (int ks = 0; ks < 2; ++ks) {
            const int koff = ks * 32 + kg * 8;
            const bf16x8 bf0 = *(const bf16x8*)(halo + ((py0 + ky) * 18 + (n + kx)) * 72 + koff);
            const bf16x8 bf1 = *(const bf16x8*)(halo + ((py0 + 1 + ky) * 18 + (n + kx)) * 72 + koff);
            #pragma unroll
            for (int mt = 0; mt < 14; ++mt) {
                const bf16x8 af = *(const bf16x8*)(wtile + (mt * 16 + n) * 72 + koff);
                acc[mt][0] = __builtin_amdgcn_mfma_f32_16x16x32_bf16(af, bf0, acc[mt][0], 0, 0, 0);
                acc[mt][1] = __builtin_amdgcn_mfma_f32_16x16x32_bf16(af, bf1, acc[mt][1], 0, 0, 0);
            }
        }
    }

    // epilogue: C/D layout col=lane&15 (pixel), row=(lane>>4)*4+reg (co)
    #pragma unroll
    for (int mt = 0; mt < 14; ++mt) {
        #pragma unroll
        for (int nt = 0; nt < 2; ++nt) {
            const int h = h0 + py0 + nt, w = w0 + n;
            #pragma unroll
            for (int r = 0; r < 4; ++r) {
                const int co = mt * 16 + kg * 4 + r;
                if (co < COFF) {
                    const float v = acc[mt][nt][r] + b_off[co];
                    conv_out[(((size_t)b * COFF + co) * Hh + h) * Ww + w] = f2bf(v);
                }
            }
        }
    }
}

// ---------- Kernel 2: modulated deformable conv ----------------------------
#define K2_TW 8
#define K2_TH 4
#define TPIX 32
#define K2_THREADS 256
#define WPAD 68

__global__ __launch_bounds__(K2_THREADS)
void dcn_kernel(const unsigned short* __restrict__ xT,
                const unsigned short* __restrict__ conv_out,
                const float* __restrict__ w_dcn,
                const float* __restrict__ b_dcn,
                float* __restrict__ out) {
    __shared__ float vbuf[72 * TPIX];
    __shared__ float wbuf[72 * WPAD];

    const int b  = blockIdx.z;
    const int h0 = blockIdx.y * K2_TH;
    const int w0 = blockIdx.x * K2_TW;
    const int t  = threadIdx.x;
    const int pix2 = t & 15;
    const int o0   = (t >> 4) * 4;

    float acc[4][2];
    #pragma unroll
    for (int i = 0; i < 4; ++i) { acc[i][0] = 0.f; acc[i][1] = 0.f; }

    for (int g = 0; g < Gg; ++g) {
        for (int e = t; e < 64 * 72; e += K2_THREADS) {
            int o  = e / 72;
            int ck = e % 72;
            wbuf[ck * WPAD + o] = w_dcn[(size_t)o * 576 + g * 72 + ck];
        }
        for (int task = t; task < 288; task += K2_THREADS) {
            const int pix = task & 31;
            const int k   = task >> 5;
            const int h = h0 + (pix >> 3);
            const int w = w0 + (pix & 7);
            const size_t obase = (((size_t)b * COFF + g * 18 + k * 2) * Hh + h) * Ww + w;
            const float dy = bf2f(conv_out[obase]);
            const float dx = bf2f(conv_out[obase + HW]);
            const float ml = bf2f(conv_out[(((size_t)b * COFF + 144 + g * 9 + k) * Hh + h) * Ww + w]);
            const float mask = 1.f / (1.f + expf(-ml));

            const float py  = (float)h + (float)(k / 3 - 1) + dy;
            const float pxx = (float)w + (float)(k % 3 - 1) + dx;
            const float y0f = floorf(py), x0f = floorf(pxx);
            const float ly = py - y0f, lx = pxx - x0f;
            const int y0 = (int)y0f, x0i = (int)x0f;
            const int y1 = y0 + 1,  x1  = x0i + 1;

            const float vy0 = (y0 >= 0 && y0 < Hh) ? 1.f : 0.f;
            const float vy1 = (y1 >= 0 && y1 < Hh) ? 1.f : 0.f;
            const float vx0 = (x0i >= 0 && x0i < Ww) ? 1.f : 0.f;
            const float vx1 = (x1 >= 0 && x1 < Ww) ? 1.f : 0.f;

            const float c00 = (1.f - ly) * (1.f - lx) * vy0 * vx0 * mask;
            const float c01 = (1.f - ly) * lx         * vy0 * vx1 * mask;
            const float c10 = ly         * (1.f - lx) * vy1 * vx0 * mask;
            const float c11 = ly         * lx         * vy1 * vx1 * mask;

            const int y0c = min(max(y0, 0), Hh - 1), y1c = min(max(y1, 0), Hh - 1);
            const int x0c = min(max(x0i, 0), Ww - 1), x1c = min(max(x1, 0), Ww - 1);

            const unsigned short* xb = xT + (size_t)b * HW * CINc + g * CGc;
            const uint4 q00 = *(const uint4*)(xb + ((size_t)y0c * Ww + x0c) * CINc);
            const uint4 q01 = *(const uint4*)(xb + ((size_t)y0c * Ww + x1c) * CINc);
            const uint4 q10 = *(const uint4*)(xb + ((size_t)y1c * Ww + x0c) * CINc);
            const uint4 q11 = *(const uint4*)(xb + ((size_t)y1c * Ww + x1c) * CINc);
            const unsigned int a00[4] = {q00.x, q00.y, q00.z, q00.w};
            const unsigned int a01[4] = {q01.x, q01.y, q01.z, q01.w};
            const unsigned int a10[4] = {q10.x, q10.y, q10.z, q10.w};
            const unsigned int a11[4] = {q11.x, q11.y, q11.z, q11.w};
            #pragma unroll
            for (int j = 0; j < 4; ++j) {
                const float vl = c00 * blo(a00[j]) + c01 * blo(a01[j])
                               + c10 * blo(a10[j]) + c11 * blo(a11[j]);
                const float vh = c00 * bhi(a00[j]) + c01 * bhi(a01[j])
                               + c10 * bhi(a10[j]) + c11 * bhi(a11[j]);
                vbuf[((2 * j) * 9 + k) * TPIX + pix]     = vl;
                vbuf[((2 * j + 1) * 9 + k) * TPIX + pix] = vh;
            }
        }
        __syncthreads();

        for (int ck = 0; ck < 72; ++ck) {
            const float4 wv = *(const float4*)&wbuf[ck * WPAD + o0];
            const float2 vv = *(const float2*)&vbuf[ck * TPIX + pix2 * 2];
            acc[0][0] += wv.x * vv.x; acc[0][1] += wv.x * vv.y;
            acc[1][0] += wv.y * vv.x; acc[1][1] += wv.y * vv.y;
            acc[2][0] += wv.z * vv.x; acc[2][1] += wv.z * vv.y;
            acc[3][0] += wv.w * vv.x; acc[3][1] += wv.w * vv.y;
        }
        __syncthreads();
    }

    #pragma unroll
    for (int i = 0; i < 4; ++i) {
        const float bias = b_dcn[o0 + i];
        #pragma unroll
        for (int j = 0; j < 2; ++j) {
            const int pix = pix2 * 2 + j;
            const int h = h0 + (pix >> 3);
            const int w = w0 + (pix & 7);
            out[(((size_t)b * CINc + o0 + i) * Hh + h) * Ww + w] = acc[i][j] + bias;
        }
    }
}

extern "C" void kernel_launch(void* const* d_in, const int* in_sizes, int n_in,
                              void* d_out, int out_size, void* d_ws, size_t ws_size,
                              hipStream_t stream) {
    const float* x     = (const float*)d_in[0];
    const float* feat  = (const float*)d_in[1];
    const float* w_off = (const float*)d_in[2];
    const float* b_off = (const float*)d_in[3];
    const float* w_dcn = (const float*)d_in[4];
    const float* b_dcn = (const float*)d_in[5];
    float* out = (float*)d_out;

    // ws layout (bf16/ushort elements):
    unsigned short* conv_out = (unsigned short*)d_ws;          // 4*216*25600 = 22,118,400
    unsigned short* featT    = conv_out + (size_t)Bn * COFF * HW;  // 6,553,600
    unsigned short* xT       = featT + (size_t)Bn * HW * CINc;     // 6,553,600
    unsigned short* wbf      = xT + (size_t)Bn * HW * CINc;        // 129,024
    // total ~70.7 MB < previously-proven 88.5 MB capacity

    nchw_to_nhwc_bf16<<<dim3(Hh, Bn, 2), 256, 0, stream>>>(feat, x, featT, xT);
    woff_repack<<<dim3((9 * MPAD * CINc + 255) / 256), 256, 0, stream>>>(w_off, wbf);
    offset_conv_mfma<<<dim3(Ww / 16, Hh / 8, Bn), 256, 0, stream>>>(featT, wbf, b_off, conv_out);
    dcn_kernel<<<dim3(Ww / K2_TW, Hh / K2_TH, Bn), K2_THREADS, 0, stream>>>(
        xT, conv_out, w_dcn, b_dcn, out);
}

// Round 3
// 284.620 us; speedup vs baseline: 11.1701x; 1.3398x over previous
//
#include <hip/hip_runtime.h>
#include <math.h>

#define Bn   4
#define CINc 64
#define Hh   160
#define Ww   160
#define Gg   8
#define CGc  8
#define HW   (Hh * Ww)      // 25600
#define COFF 216            // 3*G*KK
#define MPAD 224            // 216 padded to 14*16

typedef short bf16x8 __attribute__((ext_vector_type(8)));
typedef float f32x4  __attribute__((ext_vector_type(4)));

static __device__ __forceinline__ unsigned short f2bf(float f) {
    unsigned int u = __float_as_uint(f);
    u = (u + 0x7fffu + ((u >> 16) & 1u)) >> 16;
    return (unsigned short)u;
}
static __device__ __forceinline__ float bf2f(unsigned short s) {
    return __uint_as_float(((unsigned int)s) << 16);
}
static __device__ __forceinline__ float blo(unsigned int u) {
    return __uint_as_float(u << 16);
}
static __device__ __forceinline__ float bhi(unsigned int u) {
    return __uint_as_float(u & 0xffff0000u);
}

// ---------- Prep 1: NCHW fp32 -> NHWC bf16 for feat and x -------------------
__global__ __launch_bounds__(256)
void nchw_to_nhwc_bf16(const float* __restrict__ feat, const float* __restrict__ x,
                       unsigned short* __restrict__ featT, unsigned short* __restrict__ xT) {
    __shared__ float tile[CINc][161];   // pad 161: conflict-free transpose
    const int h = blockIdx.x;
    const int b = blockIdx.y;
    const float* src = blockIdx.z ? x : feat;
    unsigned short* dst = blockIdx.z ? xT : featT;
    const int t = threadIdx.x;
    for (int i = t; i < CINc * Ww; i += 256) {
        int ci = i / Ww, w = i % Ww;
        tile[ci][w] = src[(((size_t)b * CINc + ci) * Hh + h) * Ww + w];
    }
    __syncthreads();
    for (int i = t; i < CINc * Ww; i += 256) {
        int w = i / CINc, ci = i % CINc;
        dst[(((size_t)b * Hh + h) * Ww + w) * CINc + ci] = f2bf(tile[ci][w]);
    }
}

// ---------- Prep 2: w_off [216][64][3][3] fp32 -> [9][224][64] bf16 ---------
__global__ __launch_bounds__(256)
void woff_repack(const float* __restrict__ w_off, unsigned short* __restrict__ wbf) {
    const int e = blockIdx.x * 256 + threadIdx.x;   // 9*224*64 = 129024
    if (e >= 9 * MPAD * CINc) return;
    const int kp = e / (MPAD * CINc);
    const int r  = e % (MPAD * CINc);
    const int co = r >> 6;
    const int ci = r & 63;
    float v = (co < COFF) ? w_off[(size_t)co * 576 + ci * 9 + kp] : 0.f;
    wbf[e] = f2bf(v);
}

// ---------- Prep 3: w_dcn -> MFMA A-fragment order, permuted K --------------
// GEMM k = g*72 + kk*8 + cg  (matches vbuf write order in dcn kernel)
// wfrag[ks(18)][mt(4)][lane(64)][j(8)] = A[m = mt*16+(lane&15)][k = ks*32+(lane>>4)*8+j]
__global__ __launch_bounds__(256)
void wdcn_repack(const float* __restrict__ w_dcn, unsigned short* __restrict__ wfrag) {
    const int e = blockIdx.x * 256 + threadIdx.x;   // 18*4*64*8 = 36864
    if (e >= 18 * 4 * 64 * 8) return;
    const int j    = e & 7;
    const int lane = (e >> 3) & 63;
    const int mt   = (e >> 9) & 3;
    const int ks   = e >> 11;
    const int m = mt * 16 + (lane & 15);
    const int k = ks * 32 + (lane >> 4) * 8 + j;
    const int g = k / 72, r = k % 72;
    const int kk = r >> 3, cg = r & 7;
    const int ci = g * 8 + cg;
    wfrag[e] = f2bf(w_dcn[((size_t)m * CINc + ci) * 9 + kk]);
}

// ---------- Kernel 1: 3x3 conv as implicit-GEMM MFMA -----------------------
__global__ __launch_bounds__(256, 2)
void offset_conv_mfma(const unsigned short* __restrict__ featT,
                      const unsigned short* __restrict__ wbf,
                      const float* __restrict__ b_off,
                      unsigned short* __restrict__ conv_out) {
    __shared__ unsigned short halo[10 * 18 * 72];   // [ry][rx][ci pad 72] 25920 B
    __shared__ unsigned short wtile[MPAD * 72];     // [co][ci pad 72]     32256 B

    const int b  = blockIdx.z;
    const int h0 = blockIdx.y * 8;
    const int w0 = blockIdx.x * 16;
    const int t  = threadIdx.x;

    for (int task = t; task < 1440; task += 256) {
        const int pix = task >> 3, ch = task & 7;
        const int ry = pix / 18, rx = pix % 18;
        const int gh = h0 - 1 + ry, gw = w0 - 1 + rx;
        float4 v = make_float4(0.f, 0.f, 0.f, 0.f);
        if (gh >= 0 && gh < Hh && gw >= 0 && gw < Ww)
            v = *(const float4*)(featT + ((((size_t)b * Hh) + gh) * Ww + gw) * CINc + ch * 8);
        *(float4*)(halo + pix * 72 + ch * 8) = v;
    }

    f32x4 acc[14][2] = {};
    const int wv   = t >> 6;
    const int lane = t & 63;
    const int n    = lane & 15;
    const int kg   = lane >> 4;
    const int py0  = wv * 2;

    for (int kp = 0; kp < 9; ++kp) {
        __syncthreads();
        for (int task = t; task < 1792; task += 256) {
            const int row = task >> 3, ch = task & 7;
            *(float4*)(wtile + row * 72 + ch * 8) =
                *(const float4*)(wbf + ((size_t)kp * MPAD + row) * CINc + ch * 8);
        }
        __syncthreads();
        const int ky = kp / 3, kx = kp % 3;
        #pragma unroll
        for (int ks = 0; ks < 2; ++ks) {
            const int koff = ks * 32 + kg * 8;
            const bf16x8 bf0 = *(const bf16x8*)(halo + ((py0 + ky) * 18 + (n + kx)) * 72 + koff);
            const bf16x8 bf1 = *(const bf16x8*)(halo + ((py0 + 1 + ky) * 18 + (n + kx)) * 72 + koff);
            #pragma unroll
            for (int mt = 0; mt < 14; ++mt) {
                const bf16x8 af = *(const bf16x8*)(wtile + (mt * 16 + n) * 72 + koff);
                acc[mt][0] = __builtin_amdgcn_mfma_f32_16x16x32_bf16(af, bf0, acc[mt][0], 0, 0, 0);
                acc[mt][1] = __builtin_amdgcn_mfma_f32_16x16x32_bf16(af, bf1, acc[mt][1], 0, 0, 0);
            }
        }
    }

    #pragma unroll
    for (int mt = 0; mt < 14; ++mt) {
        #pragma unroll
        for (int nt = 0; nt < 2; ++nt) {
            const int h = h0 + py0 + nt, w = w0 + n;
            #pragma unroll
            for (int r = 0; r < 4; ++r) {
                const int co = mt * 16 + kg * 4 + r;
                if (co < COFF) {
                    const float v = acc[mt][nt][r] + b_off[co];
                    conv_out[(((size_t)b * COFF + co) * Hh + h) * Ww + w] = f2bf(v);
                }
            }
        }
    }
}

// ---------- Kernel 2: modulated deformable conv (MFMA GEMM) ----------------
#define K2_TW 8
#define K2_TH 4
#define TPIX 32
#define VROW 584   // 576 + 8 pad; keeps 16B alignment, 292dw%32=4 bank stagger

__global__ __launch_bounds__(256)
void dcn_kernel(const unsigned short* __restrict__ xT,
                const unsigned short* __restrict__ conv_out,
                const unsigned short* __restrict__ wfrag,
                const float* __restrict__ b_dcn,
                float* __restrict__ out) {
    __shared__ unsigned short vbuf[TPIX * VROW];   // [pix][k(576) pad] 37376 B

    const int b  = blockIdx.z;
    const int h0 = blockIdx.y * K2_TH;
    const int w0 = blockIdx.x * K2_TW;
    const int t  = threadIdx.x;

    // Phase 1: bilinear sampling -> vbuf (bf16), permuted K = g*72 + kk*8 + cg
    for (int task = t; task < TPIX * 72; task += 256) {   // 2304 tasks, 9 iters
        const int pix = task & 31;
        const int q   = task >> 5;          // [0,72)
        const int g   = q / 9;
        const int k   = q % 9;
        const int h = h0 + (pix >> 3);
        const int w = w0 + (pix & 7);
        const size_t obase = (((size_t)b * COFF + g * 18 + k * 2) * Hh + h) * Ww + w;
        const float dy = bf2f(conv_out[obase]);
        const float dx = bf2f(conv_out[obase + HW]);
        const float ml = bf2f(conv_out[(((size_t)b * COFF + 144 + g * 9 + k) * Hh + h) * Ww + w]);
        const float mask = 1.f / (1.f + expf(-ml));

        const float py  = (float)h + (float)(k / 3 - 1) + dy;
        const float pxx = (float)w + (float)(k % 3 - 1) + dx;
        const float y0f = floorf(py), x0f = floorf(pxx);
        const float ly = py - y0f, lx = pxx - x0f;
        const int y0 = (int)y0f, x0i = (int)x0f;
        const int y1 = y0 + 1,  x1  = x0i + 1;

        const float vy0 = (y0 >= 0 && y0 < Hh) ? 1.f : 0.f;
        const float vy1 = (y1 >= 0 && y1 < Hh) ? 1.f : 0.f;
        const float vx0 = (x0i >= 0 && x0i < Ww) ? 1.f : 0.f;
        const float vx1 = (x1 >= 0 && x1 < Ww) ? 1.f : 0.f;

        const float c00 = (1.f - ly) * (1.f - lx) * vy0 * vx0 * mask;
        const float c01 = (1.f - ly) * lx         * vy0 * vx1 * mask;
        const float c10 = ly         * (1.f - lx) * vy1 * vx0 * mask;
        const float c11 = ly         * lx         * vy1 * vx1 * mask;

        const int y0c = min(max(y0, 0), Hh - 1), y1c = min(max(y1, 0), Hh - 1);
        const int x0c = min(max(x0i, 0), Ww - 1), x1c = min(max(x1, 0), Ww - 1);

        const unsigned short* xb = xT + (size_t)b * HW * CINc + g * CGc;
        const uint4 q00 = *(const uint4*)(xb + ((size_t)y0c * Ww + x0c) * CINc);
        const uint4 q01 = *(const uint4*)(xb + ((size_t)y0c * Ww + x1c) * CINc);
        const uint4 q10 = *(const uint4*)(xb + ((size_t)y1c * Ww + x0c) * CINc);
        const uint4 q11 = *(const uint4*)(xb + ((size_t)y1c * Ww + x1c) * CINc);
        const unsigned int a00[4] = {q00.x, q00.y, q00.z, q00.w};
        const unsigned int a01[4] = {q01.x, q01.y, q01.z, q01.w};
        const unsigned int a10[4] = {q10.x, q10.y, q10.z, q10.w};
        const unsigned int a11[4] = {q11.x, q11.y, q11.z, q11.w};

        unsigned short res[8];
        #pragma unroll
        for (int j = 0; j < 4; ++j) {
            const float vl = c00 * blo(a00[j]) + c01 * blo(a01[j])
                           + c10 * blo(a10[j]) + c11 * blo(a11[j]);
            const float vh = c00 * bhi(a00[j]) + c01 * bhi(a01[j])
                           + c10 * bhi(a10[j]) + c11 * bhi(a11[j]);
            res[2 * j]     = f2bf(vl);
            res[2 * j + 1] = f2bf(vh);
        }
        // one 16B contiguous write: k_gemm = g*72 + k*8 + cg, cg contiguous
        *(uint4*)(vbuf + (size_t)pix * VROW + g * 72 + k * 8) = *(const uint4*)res;
    }
    __syncthreads();

    // Phase 2: MFMA GEMM  out[64, 32pix] = W[64,576] * vbuf[576, 32]
    const int wv    = t >> 6;
    const int lane  = t & 63;
    const int nlane = lane & 15;
    const int kg    = lane >> 4;
    const int n0    = (wv & 1) * 16;
    const int mh    = (wv >> 1) * 2;

    f32x4 acc[2] = {};
    const unsigned short* vrow = vbuf + (size_t)(n0 + nlane) * VROW;
    #pragma unroll 6
    for (int ks = 0; ks < 18; ++ks) {
        const bf16x8 bfr = *(const bf16x8*)(vrow + ks * 32 + kg * 8);
        #pragma unroll
        for (int m = 0; m < 2; ++m) {
            const bf16x8 afr = *(const bf16x8*)(wfrag + (((size_t)ks * 4 + mh + m) * 64 + lane) * 8);
            acc[m] = __builtin_amdgcn_mfma_f32_16x16x32_bf16(afr, bfr, acc[m], 0, 0, 0);
        }
    }

    // Epilogue: C/D col=lane&15 (pixel), row=(lane>>4)*4+r (out ch)
    const int pix = n0 + nlane;
    const int h = h0 + (pix >> 3);
    const int w = w0 + (pix & 7);
    #pragma unroll
    for (int m = 0; m < 2; ++m) {
        const int mt = mh + m;
        #pragma unroll
        for (int r = 0; r < 4; ++r) {
            const int o = mt * 16 + kg * 4 + r;
            out[(((size_t)b * CINc + o) * Hh + h) * Ww + w] = acc[m][r] + b_dcn[o];
        }
    }
}

extern "C" void kernel_launch(void* const* d_in, const int* in_sizes, int n_in,
                              void* d_out, int out_size, void* d_ws, size_t ws_size,
                              hipStream_t stream) {
    const float* x     = (const float*)d_in[0];
    const float* feat  = (const float*)d_in[1];
    const float* w_off = (const float*)d_in[2];
    const float* b_off = (const float*)d_in[3];
    const float* w_dcn = (const float*)d_in[4];
    const float* b_dcn = (const float*)d_in[5];
    float* out = (float*)d_out;

    // ws layout (ushort elements):
    unsigned short* conv_out = (unsigned short*)d_ws;              // 22,118,400
    unsigned short* featT    = conv_out + (size_t)Bn * COFF * HW;  // 6,553,600
    unsigned short* xT       = featT + (size_t)Bn * HW * CINc;     // 6,553,600
    unsigned short* wbf      = xT + (size_t)Bn * HW * CINc;        // 129,024
    unsigned short* wfrag    = wbf + (size_t)9 * MPAD * CINc;      // 36,864
    // total ~70.8 MB

    nchw_to_nhwc_bf16<<<dim3(Hh, Bn, 2), 256, 0, stream>>>(feat, x, featT, xT);
    woff_repack<<<dim3((9 * MPAD * CINc + 255) / 256), 256, 0, stream>>>(w_off, wbf);
    wdcn_repack<<<dim3((18 * 4 * 64 * 8 + 255) / 256), 256, 0, stream>>>(w_dcn, wfrag);
    offset_conv_mfma<<<dim3(Ww / 16, Hh / 8, Bn), 256, 0, stream>>>(featT, wbf, b_off, conv_out);
    dcn_kernel<<<dim3(Ww / K2_TW, Hh / K2_TH, Bn), 256, 0, stream>>>(
        xT, conv_out, wfrag, b_dcn, out);
}

// Round 4
// 260.973 us; speedup vs baseline: 12.1823x; 1.0906x over previous
//
#include <hip/hip_runtime.h>
#include <math.h>

#define Bn   4
#define CINc 64
#define Hh   160
#define Ww   160
#define Gg   8
#define CGc  8
#define HW   (Hh * Ww)      // 25600
#define COFF 216            // 3*G*KK
#define K1M  112            // co per block in offset conv (7 m-tiles)

typedef short bf16x8 __attribute__((ext_vector_type(8)));
typedef float f32x4  __attribute__((ext_vector_type(4)));

static __device__ __forceinline__ unsigned short f2bf(float f) {
    unsigned int u = __float_as_uint(f);
    u = (u + 0x7fffu + ((u >> 16) & 1u)) >> 16;
    return (unsigned short)u;
}
static __device__ __forceinline__ float bf2f(unsigned short s) {
    return __uint_as_float(((unsigned int)s) << 16);
}
static __device__ __forceinline__ float blo(unsigned int u) {
    return __uint_as_float(u << 16);
}
static __device__ __forceinline__ float bhi(unsigned int u) {
    return __uint_as_float(u & 0xffff0000u);
}

// ---------- Prep 1: NCHW fp32 -> bf16; feat: [b][pix][64], x: [b][g][pix][8]
__global__ __launch_bounds__(256)
void nchw_to_nhwc_bf16(const float* __restrict__ feat, const float* __restrict__ x,
                       unsigned short* __restrict__ featT, unsigned short* __restrict__ xG) {
    __shared__ float tile[CINc][161];   // pad 161: conflict-free transpose
    const int h = blockIdx.x;
    const int b = blockIdx.y;
    const float* src = blockIdx.z ? x : feat;
    const int t = threadIdx.x;
    for (int i = t; i < CINc * Ww; i += 256) {
        int ci = i / Ww, w = i % Ww;
        tile[ci][w] = src[(((size_t)b * CINc + ci) * Hh + h) * Ww + w];
    }
    __syncthreads();
    if (blockIdx.z) {
        // x -> group-major NHWC8: xG[((b*8+g)*HW + h*W + w)*8 + cg]
        for (int i = t; i < CINc * Ww; i += 256) {
            int g = i / (Ww * 8);
            int r = i % (Ww * 8);
            int w = r >> 3, cg = r & 7;
            xG[(((size_t)b * Gg + g) * HW + h * Ww + w) * 8 + cg] = f2bf(tile[g * 8 + cg][w]);
        }
    } else {
        for (int i = t; i < CINc * Ww; i += 256) {
            int w = i / CINc, ci = i % CINc;
            featT[(((size_t)b * Hh + h) * Ww + w) * CINc + ci] = f2bf(tile[ci][w]);
        }
    }
}

// ---------- Prep 2: w_off -> MFMA A-fragment order ---------------------------
// wofrag[mc(2)][kp(9)][ks(2)][mt(7)][lane(64)][j(8)]
//   = A[co = mc*112 + mt*16 + (lane&15)][ci = ks*32 + (lane>>4)*8 + j] at tap kp
__global__ __launch_bounds__(256)
void woff_repack(const float* __restrict__ w_off, unsigned short* __restrict__ wofrag) {
    const int e = blockIdx.x * 256 + threadIdx.x;   // 2*9*2*7*512 = 129024
    if (e >= 2 * 9 * 2 * 7 * 512) return;
    const int j    = e & 7;
    const int lane = (e >> 3) & 63;
    const int mrest = e >> 9;
    const int mt = mrest % 7;
    const int q2 = mrest / 7;
    const int ks = q2 & 1;
    const int q3 = q2 >> 1;
    const int kp = q3 % 9;
    const int mc = q3 / 9;
    const int co = mc * K1M + mt * 16 + (lane & 15);
    const int ci = ks * 32 + (lane >> 4) * 8 + j;
    float v = (co < COFF) ? w_off[(size_t)co * 576 + ci * 9 + kp] : 0.f;
    wofrag[e] = f2bf(v);
}

// ---------- Prep 3: w_dcn -> MFMA A-fragment order, permuted K ---------------
__global__ __launch_bounds__(256)
void wdcn_repack(const float* __restrict__ w_dcn, unsigned short* __restrict__ wfrag) {
    const int e = blockIdx.x * 256 + threadIdx.x;   // 18*4*64*8 = 36864
    if (e >= 18 * 4 * 64 * 8) return;
    const int j    = e & 7;
    const int lane = (e >> 3) & 63;
    const int mt   = (e >> 9) & 3;
    const int ks   = e >> 11;
    const int m = mt * 16 + (lane & 15);
    const int k = ks * 32 + (lane >> 4) * 8 + j;
    const int g = k / 72, r = k % 72;
    const int kk = r >> 3, cg = r & 7;
    const int ci = g * 8 + cg;
    wfrag[e] = f2bf(w_dcn[((size_t)m * CINc + ci) * 9 + kk]);
}

// ---------- Kernel 1: 3x3 conv, A-fragments from global (no weight LDS) -----
// block: 256 thr (4 waves), pixel tile 16x8 (N=128), M=112 per block.
// sigmoid fused for mask channels (co >= 144).
__global__ __launch_bounds__(256, 3)
void offset_conv_mfma(const unsigned short* __restrict__ featT,
                      const unsigned short* __restrict__ wofrag,
                      const float* __restrict__ b_off,
                      unsigned short* __restrict__ conv_out) {
    __shared__ unsigned short halo[10 * 18 * 72];   // [ry][rx][ci pad 72] 25920 B

    const int b  = blockIdx.z & 3;
    const int mc = blockIdx.z >> 2;
    const int h0 = blockIdx.y * 8;
    const int w0 = blockIdx.x * 16;
    const int t  = threadIdx.x;

    for (int task = t; task < 1440; task += 256) {
        const int pix = task >> 3, ch = task & 7;
        const int ry = pix / 18, rx = pix % 18;
        const int gh = h0 - 1 + ry, gw = w0 - 1 + rx;
        float4 v = make_float4(0.f, 0.f, 0.f, 0.f);
        if (gh >= 0 && gh < Hh && gw >= 0 && gw < Ww)
            v = *(const float4*)(featT + ((((size_t)b * Hh) + gh) * Ww + gw) * CINc + ch * 8);
        *(float4*)(halo + pix * 72 + ch * 8) = v;
    }
    __syncthreads();

    const int wv   = t >> 6;
    const int lane = t & 63;
    const int n    = lane & 15;
    const int kg   = lane >> 4;
    const int py0  = wv * 2;

    f32x4 acc[7][2] = {};
    for (int kp = 0; kp < 9; ++kp) {
        const int ky = kp / 3, kx = kp % 3;
        #pragma unroll
        for (int ks = 0; ks < 2; ++ks) {
            const int koff = ks * 32 + kg * 8;
            const bf16x8 bf0 = *(const bf16x8*)(halo + ((py0 + ky) * 18 + (n + kx)) * 72 + koff);
            const bf16x8 bf1 = *(const bf16x8*)(halo + ((py0 + 1 + ky) * 18 + (n + kx)) * 72 + koff);
            const unsigned short* abase =
                wofrag + ((size_t)(((mc * 9 + kp) * 2 + ks) * 7) * 64 + lane) * 8;
            #pragma unroll
            for (int mt = 0; mt < 7; ++mt) {
                const bf16x8 af = *(const bf16x8*)(abase + (size_t)mt * 512);
                acc[mt][0] = __builtin_amdgcn_mfma_f32_16x16x32_bf16(af, bf0, acc[mt][0], 0, 0, 0);
                acc[mt][1] = __builtin_amdgcn_mfma_f32_16x16x32_bf16(af, bf1, acc[mt][1], 0, 0, 0);
            }
        }
    }

    #pragma unroll
    for (int mt = 0; mt < 7; ++mt) {
        #pragma unroll
        for (int nt = 0; nt < 2; ++nt) {
            const int h = h0 + py0 + nt, w = w0 + n;
            #pragma unroll
            for (int r = 0; r < 4; ++r) {
                const int co = mc * K1M + mt * 16 + kg * 4 + r;
                if (co < COFF) {
                    float v = acc[mt][nt][r] + b_off[co];
                    if (co >= 144) v = 1.f / (1.f + expf(-v));   // fused sigmoid for mask
                    conv_out[(((size_t)b * COFF + co) * Hh + h) * Ww + w] = f2bf(v);
                }
            }
        }
    }
}

// ---------- Kernel 2: modulated deformable conv (MFMA GEMM) ----------------
#define K2_TW 8
#define K2_TH 4
#define TPIX 32
#define VROW 584   // 576 + 8 pad

__global__ __launch_bounds__(256, 4)
void dcn_kernel(const unsigned short* __restrict__ xG,
                const unsigned short* __restrict__ conv_out,
                const unsigned short* __restrict__ wfrag,
                const float* __restrict__ b_dcn,
                float* __restrict__ out) {
    __shared__ unsigned short vbuf[TPIX * VROW];   // [pix][k(576) pad] 37376 B

    const int b  = blockIdx.z;
    const int h0 = blockIdx.y * K2_TH;
    const int w0 = blockIdx.x * K2_TW;
    const int t  = threadIdx.x;

    // Phase 1: bilinear sampling -> vbuf (bf16), permuted K = g*72 + kk*8 + cg
    #pragma unroll 3
    for (int it = 0; it < 9; ++it) {
        const int task = t + it * 256;
        const int pix = task & 31;
        const int q   = task >> 5;          // [0,72)
        const int g   = q / 9;
        const int k   = q % 9;
        const int h = h0 + (pix >> 3);
        const int w = w0 + (pix & 7);
        const size_t obase = (((size_t)b * COFF + g * 18 + k * 2) * Hh + h) * Ww + w;
        const float dy = bf2f(conv_out[obase]);
        const float dx = bf2f(conv_out[obase + HW]);
        const float mask = bf2f(conv_out[(((size_t)b * COFF + 144 + g * 9 + k) * Hh + h) * Ww + w]);

        const float py  = (float)h + (float)(k / 3 - 1) + dy;
        const float pxx = (float)w + (float)(k % 3 - 1) + dx;
        const float y0f = floorf(py), x0f = floorf(pxx);
        const float ly = py - y0f, lx = pxx - x0f;
        const int y0 = (int)y0f, x0i = (int)x0f;
        const int y1 = y0 + 1,  x1  = x0i + 1;

        const float vy0 = (y0 >= 0 && y0 < Hh) ? 1.f : 0.f;
        const float vy1 = (y1 >= 0 && y1 < Hh) ? 1.f : 0.f;
        const float vx0 = (x0i >= 0 && x0i < Ww) ? 1.f : 0.f;
        const float vx1 = (x1 >= 0 && x1 < Ww) ? 1.f : 0.f;

        const float c00 = (1.f - ly) * (1.f - lx) * vy0 * vx0 * mask;
        const float c01 = (1.f - ly) * lx         * vy0 * vx1 * mask;
        const float c10 = ly         * (1.f - lx) * vy1 * vx0 * mask;
        const float c11 = ly         * lx         * vy1 * vx1 * mask;

        const int y0c = min(max(y0, 0), Hh - 1), y1c = min(max(y1, 0), Hh - 1);
        const int x0c = min(max(x0i, 0), Ww - 1), x1c = min(max(x1, 0), Ww - 1);

        // group-major records: 16 B per (pix,g); lanes (consecutive pix) coalesce
        const unsigned short* xb = xG + ((size_t)b * Gg + g) * HW * 8;
        const uint4 q00 = *(const uint4*)(xb + ((size_t)y0c * Ww + x0c) * 8);
        const uint4 q01 = *(const uint4*)(xb + ((size_t)y0c * Ww + x1c) * 8);
        const uint4 q10 = *(const uint4*)(xb + ((size_t)y1c * Ww + x0c) * 8);
        const uint4 q11 = *(const uint4*)(xb + ((size_t)y1c * Ww + x1c) * 8);
        const unsigned int a00[4] = {q00.x, q00.y, q00.z, q00.w};
        const unsigned int a01[4] = {q01.x, q01.y, q01.z, q01.w};
        const unsigned int a10[4] = {q10.x, q10.y, q10.z, q10.w};
        const unsigned int a11[4] = {q11.x, q11.y, q11.z, q11.w};

        unsigned short res[8];
        #pragma unroll
        for (int j = 0; j < 4; ++j) {
            const float vl = c00 * blo(a00[j]) + c01 * blo(a01[j])
                           + c10 * blo(a10[j]) + c11 * blo(a11[j]);
            const float vh = c00 * bhi(a00[j]) + c01 * bhi(a01[j])
                           + c10 * bhi(a10[j]) + c11 * bhi(a11[j]);
            res[2 * j]     = f2bf(vl);
            res[2 * j + 1] = f2bf(vh);
        }
        *(uint4*)(vbuf + (size_t)pix * VROW + g * 72 + k * 8) = *(const uint4*)res;
    }
    __syncthreads();

    // Phase 2: MFMA GEMM  out[64, 32pix] = W[64,576] * vbuf[576, 32]
    const int wv    = t >> 6;
    const int lane  = t & 63;
    const int nlane = lane & 15;
    const int kg    = lane >> 4;
    const int n0    = (wv & 1) * 16;
    const int mh    = (wv >> 1) * 2;

    f32x4 acc[2] = {};
    const unsigned short* vrow = vbuf + (size_t)(n0 + nlane) * VROW;
    #pragma unroll 6
    for (int ks = 0; ks < 18; ++ks) {
        const bf16x8 bfr = *(const bf16x8*)(vrow + ks * 32 + kg * 8);
        #pragma unroll
        for (int m = 0; m < 2; ++m) {
            const bf16x8 afr = *(const bf16x8*)(wfrag + (((size_t)ks * 4 + mh + m) * 64 + lane) * 8);
            acc[m] = __builtin_amdgcn_mfma_f32_16x16x32_bf16(afr, bfr, acc[m], 0, 0, 0);
        }
    }

    const int pix = n0 + nlane;
    const int h = h0 + (pix >> 3);
    const int w = w0 + (pix & 7);
    #pragma unroll
    for (int m = 0; m < 2; ++m) {
        const int mt = mh + m;
        #pragma unroll
        for (int r = 0; r < 4; ++r) {
            const int o = mt * 16 + kg * 4 + r;
            out[(((size_t)b * CINc + o) * Hh + h) * Ww + w] = acc[m][r] + b_dcn[o];
        }
    }
}

extern "C" void kernel_launch(void* const* d_in, const int* in_sizes, int n_in,
                              void* d_out, int out_size, void* d_ws, size_t ws_size,
                              hipStream_t stream) {
    const float* x     = (const float*)d_in[0];
    const float* feat  = (const float*)d_in[1];
    const float* w_off = (const float*)d_in[2];
    const float* b_off = (const float*)d_in[3];
    const float* w_dcn = (const float*)d_in[4];
    const float* b_dcn = (const float*)d_in[5];
    float* out = (float*)d_out;

    // ws layout (ushort elements):
    unsigned short* conv_out = (unsigned short*)d_ws;              // 22,118,400
    unsigned short* featT    = conv_out + (size_t)Bn * COFF * HW;  // 6,553,600
    unsigned short* xG       = featT + (size_t)Bn * HW * CINc;     // 6,553,600
    unsigned short* wofrag   = xG + (size_t)Bn * HW * CINc;        // 129,024
    unsigned short* wfrag    = wofrag + (size_t)2 * 9 * 2 * 7 * 512; // 36,864
    // total ~70.8 MB

    nchw_to_nhwc_bf16<<<dim3(Hh, Bn, 2), 256, 0, stream>>>(feat, x, featT, xG);
    woff_repack<<<dim3((2 * 9 * 2 * 7 * 512 + 255) / 256), 256, 0, stream>>>(w_off, wofrag);
    wdcn_repack<<<dim3((18 * 4 * 64 * 8 + 255) / 256), 256, 0, stream>>>(w_dcn, wfrag);
    offset_conv_mfma<<<dim3(Ww / 16, Hh / 8, Bn * 2), 256, 0, stream>>>(
        featT, wofrag, b_off, conv_out);
    dcn_kernel<<<dim3(Ww / K2_TW, Hh / K2_TH, Bn), 256, 0, stream>>>(
        xG, conv_out, wfrag, b_dcn, out);
}

// Round 5
// 259.608 us; speedup vs baseline: 12.2463x; 1.0053x over previous
//
#include <hip/hip_runtime.h>
#include <math.h>

#define Bn   4
#define CINc 64
#define Hh   160
#define Ww   160
#define Gg   8
#define CGc  8
#define HW   (Hh * Ww)      // 25600
#define COFF 216            // 3*G*KK
#define K1M  112            // co per block in offset conv (7 m-tiles)

typedef short bf16x8 __attribute__((ext_vector_type(8)));
typedef float f32x4  __attribute__((ext_vector_type(4)));

static __device__ __forceinline__ unsigned short f2bf(float f) {
    unsigned int u = __float_as_uint(f);
    u = (u + 0x7fffu + ((u >> 16) & 1u)) >> 16;
    return (unsigned short)u;
}
static __device__ __forceinline__ float bf2f(unsigned short s) {
    return __uint_as_float(((unsigned int)s) << 16);
}
static __device__ __forceinline__ float blo(unsigned int u) {
    return __uint_as_float(u << 16);
}
static __device__ __forceinline__ float bhi(unsigned int u) {
    return __uint_as_float(u & 0xffff0000u);
}

// ---------- Prep 1: NCHW fp32 -> bf16; feat: [b][pix][64], x: [b][g][pix][8]
__global__ __launch_bounds__(256)
void nchw_to_nhwc_bf16(const float* __restrict__ feat, const float* __restrict__ x,
                       unsigned short* __restrict__ featT, unsigned short* __restrict__ xG) {
    __shared__ float tile[CINc][161];
    const int h = blockIdx.x;
    const int b = blockIdx.y;
    const float* src = blockIdx.z ? x : feat;
    const int t = threadIdx.x;
    for (int i = t; i < CINc * Ww; i += 256) {
        int ci = i / Ww, w = i % Ww;
        tile[ci][w] = src[(((size_t)b * CINc + ci) * Hh + h) * Ww + w];
    }
    __syncthreads();
    if (blockIdx.z) {
        for (int i = t; i < CINc * Ww; i += 256) {
            int g = i / (Ww * 8);
            int r = i % (Ww * 8);
            int w = r >> 3, cg = r & 7;
            xG[(((size_t)b * Gg + g) * HW + h * Ww + w) * 8 + cg] = f2bf(tile[g * 8 + cg][w]);
        }
    } else {
        for (int i = t; i < CINc * Ww; i += 256) {
            int w = i / CINc, ci = i % CINc;
            featT[(((size_t)b * Hh + h) * Ww + w) * CINc + ci] = f2bf(tile[ci][w]);
        }
    }
}

// ---------- Prep 2: both weight repacks in one launch -----------------------
// wofrag[mc(2)][kp(9)][ks(2)][mt(7)][lane(64)][j(8)]
//   = A[co = mc*112 + mt*16 + (lane&15)][ci = ks*32 + (lane>>4)*8 + j] at tap kp
// wfrag[ks(18)][mt(4)][lane(64)][j(8)]: dcn GEMM A, permuted K = g*72+kk*8+cg
__global__ __launch_bounds__(256)
void weights_repack(const float* __restrict__ w_off, const float* __restrict__ w_dcn,
                    unsigned short* __restrict__ wofrag, unsigned short* __restrict__ wfrag) {
    const int e = blockIdx.x * 256 + threadIdx.x;
    if (e < 2 * 9 * 2 * 7 * 512) {
        const int j    = e & 7;
        const int lane = (e >> 3) & 63;
        const int mrest = e >> 9;
        const int mt = mrest % 7;
        const int q2 = mrest / 7;
        const int ks = q2 & 1;
        const int q3 = q2 >> 1;
        const int kp = q3 % 9;
        const int mc = q3 / 9;
        const int co = mc * K1M + mt * 16 + (lane & 15);
        const int ci = ks * 32 + (lane >> 4) * 8 + j;
        float v = (co < COFF) ? w_off[(size_t)co * 576 + ci * 9 + kp] : 0.f;
        wofrag[e] = f2bf(v);
    } else if (e < 2 * 9 * 2 * 7 * 512 + 18 * 4 * 64 * 8) {
        const int e2   = e - 2 * 9 * 2 * 7 * 512;
        const int j    = e2 & 7;
        const int lane = (e2 >> 3) & 63;
        const int mt   = (e2 >> 9) & 3;
        const int ks   = e2 >> 11;
        const int m = mt * 16 + (lane & 15);
        const int k = ks * 32 + (lane >> 4) * 8 + j;
        const int g = k / 72, r = k % 72;
        const int kk = r >> 3, cg = r & 7;
        const int ci = g * 8 + cg;
        wfrag[e2] = f2bf(w_dcn[((size_t)m * CINc + ci) * 9 + kk]);
    }
}

// ---------- Kernel 1: 3x3 conv, A-frags double-buffered from global ---------
// Output layout packed for dcn: conv_pk[b][gk(72)][pix][4] = {dy,dx,mask,pad}
__global__ __launch_bounds__(256, 3)
void offset_conv_mfma(const unsigned short* __restrict__ featT,
                      const unsigned short* __restrict__ wofrag,
                      const float* __restrict__ b_off,
                      unsigned short* __restrict__ conv_pk) {
    __shared__ unsigned short halo[10 * 18 * 72];   // 25920 B

    const int b  = blockIdx.z & 3;
    const int mc = blockIdx.z >> 2;
    const int h0 = blockIdx.y * 8;
    const int w0 = blockIdx.x * 16;
    const int t  = threadIdx.x;

    for (int task = t; task < 1440; task += 256) {
        const int pix = task >> 3, ch = task & 7;
        const int ry = pix / 18, rx = pix % 18;
        const int gh = h0 - 1 + ry, gw = w0 - 1 + rx;
        float4 v = make_float4(0.f, 0.f, 0.f, 0.f);
        if (gh >= 0 && gh < Hh && gw >= 0 && gw < Ww)
            v = *(const float4*)(featT + ((((size_t)b * Hh) + gh) * Ww + gw) * CINc + ch * 8);
        *(float4*)(halo + pix * 72 + ch * 8) = v;
    }
    __syncthreads();

    const int wv   = t >> 6;
    const int lane = t & 63;
    const int n    = lane & 15;
    const int kg   = lane >> 4;
    const int py0  = wv * 2;

    // A base for step s: wofrag + ((mc*18 + s)*448 + lane)*8, mt stride 512
    const unsigned short* abase0 = wofrag + ((size_t)(mc * 18) * 448 + lane) * 8;

    f32x4 acc[7][2] = {};
    bf16x8 abuf[2][7];
    #pragma unroll
    for (int mt = 0; mt < 7; ++mt)
        abuf[0][mt] = *(const bf16x8*)(abase0 + (size_t)mt * 512);

    #pragma unroll 2
    for (int s = 0; s < 18; ++s) {
        const int cb = s & 1, nb = cb ^ 1;
        if (s < 17) {
            const unsigned short* an = abase0 + (size_t)(s + 1) * 3584;
            #pragma unroll
            for (int mt = 0; mt < 7; ++mt)
                abuf[nb][mt] = *(const bf16x8*)(an + (size_t)mt * 512);
        }
        const int kp = s >> 1, ks = s & 1;
        const int ky = kp / 3, kx = kp % 3;
        const int koff = ks * 32 + kg * 8;
        const bf16x8 bf0 = *(const bf16x8*)(halo + ((py0 + ky) * 18 + (n + kx)) * 72 + koff);
        const bf16x8 bf1 = *(const bf16x8*)(halo + ((py0 + 1 + ky) * 18 + (n + kx)) * 72 + koff);
        #pragma unroll
        for (int mt = 0; mt < 7; ++mt) {
            acc[mt][0] = __builtin_amdgcn_mfma_f32_16x16x32_bf16(abuf[cb][mt], bf0, acc[mt][0], 0, 0, 0);
            acc[mt][1] = __builtin_amdgcn_mfma_f32_16x16x32_bf16(abuf[cb][mt], bf1, acc[mt][1], 0, 0, 0);
        }
    }

    // epilogue: C/D col=lane&15 (pixel), row=(lane>>4)*4+r (co); scatter to packed
    #pragma unroll
    for (int mt = 0; mt < 7; ++mt) {
        #pragma unroll
        for (int nt = 0; nt < 2; ++nt) {
            const int h = h0 + py0 + nt, w = w0 + n;
            const int p = h * Ww + w;
            #pragma unroll
            for (int r = 0; r < 4; ++r) {
                const int co = mc * K1M + mt * 16 + kg * 4 + r;
                if (co < COFF) {
                    float v = acc[mt][nt][r] + b_off[co];
                    int gk, type;
                    if (co >= 144) { v = 1.f / (1.f + expf(-v)); gk = co - 144; type = 2; }
                    else           { gk = co >> 1; type = co & 1; }
                    conv_pk[(((size_t)b * 72 + gk) * HW + p) * 4 + type] = f2bf(v);
                }
            }
        }
    }
}

// ---------- Kernel 2: modulated deformable conv (MFMA GEMM) ----------------
#define K2_TW 8
#define K2_TH 4
#define TPIX 32
#define VROW 584   // 576 + 8 pad

__global__ __launch_bounds__(256, 4)
void dcn_kernel(const unsigned short* __restrict__ xG,
                const unsigned short* __restrict__ conv_pk,
                const unsigned short* __restrict__ wfrag,
                const float* __restrict__ b_dcn,
                float* __restrict__ out) {
    __shared__ unsigned short vbuf[TPIX * VROW];   // 37376 B

    const int b  = blockIdx.z;
    const int h0 = blockIdx.y * K2_TH;
    const int w0 = blockIdx.x * K2_TW;
    const int t  = threadIdx.x;

    // Phase 1: bilinear sampling -> vbuf (bf16), permuted K = g*72 + kk*8 + cg
    #pragma unroll 3
    for (int it = 0; it < 9; ++it) {
        const int task = t + it * 256;
        const int pix = task & 31;
        const int q   = task >> 5;          // [0,72) = g*9 + k
        const int g   = q / 9;
        const int k   = q % 9;
        const int h = h0 + (pix >> 3);
        const int w = w0 + (pix & 7);

        // one 8B read: {dy, dx, mask(sigmoided), pad}
        const ushort4 o4 = *(const ushort4*)(conv_pk + (((size_t)b * 72 + q) * HW + h * Ww + w) * 4);
        const float dy = bf2f(o4.x);
        const float dx = bf2f(o4.y);
        const float mask = bf2f(o4.z);

        const float py  = (float)h + (float)(k / 3 - 1) + dy;
        const float pxx = (float)w + (float)(k % 3 - 1) + dx;
        const float y0f = floorf(py), x0f = floorf(pxx);
        const float ly = py - y0f, lx = pxx - x0f;
        const int y0 = (int)y0f, x0i = (int)x0f;
        const int y1 = y0 + 1,  x1  = x0i + 1;

        const float vy0 = (y0 >= 0 && y0 < Hh) ? 1.f : 0.f;
        const float vy1 = (y1 >= 0 && y1 < Hh) ? 1.f : 0.f;
        const float vx0 = (x0i >= 0 && x0i < Ww) ? 1.f : 0.f;
        const float vx1 = (x1 >= 0 && x1 < Ww) ? 1.f : 0.f;

        const float c00 = (1.f - ly) * (1.f - lx) * vy0 * vx0 * mask;
        const float c01 = (1.f - ly) * lx         * vy0 * vx1 * mask;
        const float c10 = ly         * (1.f - lx) * vy1 * vx0 * mask;
        const float c11 = ly         * lx         * vy1 * vx1 * mask;

        const int y0c = min(max(y0, 0), Hh - 1), y1c = min(max(y1, 0), Hh - 1);
        const int x0c = min(max(x0i, 0), Ww - 1), x1c = min(max(x1, 0), Ww - 1);

        const unsigned short* xb = xG + ((size_t)b * Gg + g) * HW * 8;
        const uint4 q00 = *(const uint4*)(xb + ((size_t)y0c * Ww + x0c) * 8);
        const uint4 q01 = *(const uint4*)(xb + ((size_t)y0c * Ww + x1c) * 8);
        const uint4 q10 = *(const uint4*)(xb + ((size_t)y1c * Ww + x0c) * 8);
        const uint4 q11 = *(const uint4*)(xb + ((size_t)y1c * Ww + x1c) * 8);
        const unsigned int a00[4] = {q00.x, q00.y, q00.z, q00.w};
        const unsigned int a01[4] = {q01.x, q01.y, q01.z, q01.w};
        const unsigned int a10[4] = {q10.x, q10.y, q10.z, q10.w};
        const unsigned int a11[4] = {q11.x, q11.y, q11.z, q11.w};

        unsigned short res[8];
        #pragma unroll
        for (int j = 0; j < 4; ++j) {
            const float vl = c00 * blo(a00[j]) + c01 * blo(a01[j])
                           + c10 * blo(a10[j]) + c11 * blo(a11[j]);
            const float vh = c00 * bhi(a00[j]) + c01 * bhi(a01[j])
                           + c10 * bhi(a10[j]) + c11 * bhi(a11[j]);
            res[2 * j]     = f2bf(vl);
            res[2 * j + 1] = f2bf(vh);
        }
        *(uint4*)(vbuf + (size_t)pix * VROW + g * 72 + k * 8) = *(const uint4*)res;
    }
    __syncthreads();

    // Phase 2: MFMA GEMM with A double-buffer
    const int wv    = t >> 6;
    const int lane  = t & 63;
    const int nlane = lane & 15;
    const int kg    = lane >> 4;
    const int n0    = (wv & 1) * 16;
    const int mh    = (wv >> 1) * 2;

    f32x4 acc[2] = {};
    const unsigned short* vrow = vbuf + (size_t)(n0 + nlane) * VROW;
    bf16x8 af[2][2];
    #pragma unroll
    for (int m = 0; m < 2; ++m)
        af[0][m] = *(const bf16x8*)(wfrag + (((size_t)0 * 4 + mh + m) * 64 + lane) * 8);

    #pragma unroll 2
    for (int ks = 0; ks < 18; ++ks) {
        const int cb = ks & 1, nb = cb ^ 1;
        if (ks < 17) {
            #pragma unroll
            for (int m = 0; m < 2; ++m)
                af[nb][m] = *(const bf16x8*)(wfrag + (((size_t)(ks + 1) * 4 + mh + m) * 64 + lane) * 8);
        }
        const bf16x8 bfr = *(const bf16x8*)(vrow + ks * 32 + kg * 8);
        acc[0] = __builtin_amdgcn_mfma_f32_16x16x32_bf16(af[cb][0], bfr, acc[0], 0, 0, 0);
        acc[1] = __builtin_amdgcn_mfma_f32_16x16x32_bf16(af[cb][1], bfr, acc[1], 0, 0, 0);
    }

    const int pix = n0 + nlane;
    const int h = h0 + (pix >> 3);
    const int w = w0 + (pix & 7);
    #pragma unroll
    for (int m = 0; m < 2; ++m) {
        const int mt = mh + m;
        #pragma unroll
        for (int r = 0; r < 4; ++r) {
            const int o = mt * 16 + kg * 4 + r;
            out[(((size_t)b * CINc + o) * Hh + h) * Ww + w] = acc[m][r] + b_dcn[o];
        }
    }
}

extern "C" void kernel_launch(void* const* d_in, const int* in_sizes, int n_in,
                              void* d_out, int out_size, void* d_ws, size_t ws_size,
                              hipStream_t stream) {
    const float* x     = (const float*)d_in[0];
    const float* feat  = (const float*)d_in[1];
    const float* w_off = (const float*)d_in[2];
    const float* b_off = (const float*)d_in[3];
    const float* w_dcn = (const float*)d_in[4];
    const float* b_dcn = (const float*)d_in[5];
    float* out = (float*)d_out;

    // ws layout (ushort elements):
    unsigned short* conv_pk = (unsigned short*)d_ws;                 // 4*72*25600*4 = 29,491,200
    unsigned short* featT   = conv_pk + (size_t)Bn * 72 * HW * 4;    // 6,553,600
    unsigned short* xG      = featT + (size_t)Bn * HW * CINc;        // 6,553,600
    unsigned short* wofrag  = xG + (size_t)Bn * HW * CINc;           // 129,024
    unsigned short* wfrag   = wofrag + (size_t)2 * 9 * 2 * 7 * 512;  // 36,864
    // total ~85.5 MB (ws >= 88.5 MB proven in round 0)

    nchw_to_nhwc_bf16<<<dim3(Hh, Bn, 2), 256, 0, stream>>>(feat, x, featT, xG);
    weights_repack<<<dim3((129024 + 36864 + 255) / 256), 256, 0, stream>>>(
        w_off, w_dcn, wofrag, wfrag);
    offset_conv_mfma<<<dim3(Ww / 16, Hh / 8, Bn * 2), 256, 0, stream>>>(
        featT, wofrag, b_off, conv_pk);
    dcn_kernel<<<dim3(Ww / K2_TW, Hh / K2_TH, Bn), 256, 0, stream>>>(
        xG, conv_pk, wfrag, b_dcn, out);
}

// Round 6
// 254.288 us; speedup vs baseline: 12.5025x; 1.0209x over previous
//
#include <hip/hip_runtime.h>
#include <math.h>

#define Bn   4
#define CINc 64
#define Hh   160
#define Ww   160
#define Gg   8
#define CGc  8
#define HW   (Hh * Ww)      // 25600
#define COFF 216            // 3*G*KK
#define K1M  112            // co per block in offset conv (7 m-tiles)

typedef short bf16x8 __attribute__((ext_vector_type(8)));
typedef float f32x4  __attribute__((ext_vector_type(4)));

static __device__ __forceinline__ unsigned short f2bf(float f) {
    unsigned int u = __float_as_uint(f);
    u = (u + 0x7fffu + ((u >> 16) & 1u)) >> 16;
    return (unsigned short)u;
}
static __device__ __forceinline__ float bf2f(unsigned short s) {
    return __uint_as_float(((unsigned int)s) << 16);
}
static __device__ __forceinline__ float blo(unsigned int u) {
    return __uint_as_float(u << 16);
}
static __device__ __forceinline__ float bhi(unsigned int u) {
    return __uint_as_float(u & 0xffff0000u);
}

// ---------- Fused prep: transposes + both weight repacks (1 launch) ---------
// blocks [0,640):   feat -> featT [b][pix][64]
// blocks [640,1280): x   -> xG    [b][g][pix][8]
// blocks [1280,1280+WB): weight repacks (grid-stride over 165888 elems)
#define WB 162
__global__ __launch_bounds__(256)
void prep_kernel(const float* __restrict__ feat, const float* __restrict__ x,
                 const float* __restrict__ w_off, const float* __restrict__ w_dcn,
                 unsigned short* __restrict__ featT, unsigned short* __restrict__ xG,
                 unsigned short* __restrict__ wofrag, unsigned short* __restrict__ wfrag) {
    const int blk = blockIdx.x;
    const int t = threadIdx.x;
    if (blk < 1280) {
        __shared__ float tile[CINc][161];
        const int isx = blk >= 640;
        const int rem = isx ? blk - 640 : blk;
        const int b = rem / Hh;
        const int h = rem % Hh;
        const float* src = isx ? x : feat;
        for (int i = t; i < CINc * Ww; i += 256) {
            int ci = i / Ww, w = i % Ww;
            tile[ci][w] = src[(((size_t)b * CINc + ci) * Hh + h) * Ww + w];
        }
        __syncthreads();
        if (isx) {
            for (int i = t; i < CINc * Ww; i += 256) {
                int g = i / (Ww * 8);
                int r = i % (Ww * 8);
                int w = r >> 3, cg = r & 7;
                xG[(((size_t)b * Gg + g) * HW + h * Ww + w) * 8 + cg] = f2bf(tile[g * 8 + cg][w]);
            }
        } else {
            for (int i = t; i < CINc * Ww; i += 256) {
                int w = i / CINc, ci = i % CINc;
                featT[(((size_t)b * Hh + h) * Ww + w) * CINc + ci] = f2bf(tile[ci][w]);
            }
        }
    } else {
        // weights: 129024 wofrag + 36864 wfrag = 165888 elems, grid-stride
        for (int e = (blk - 1280) * 256 + t; e < 129024 + 36864; e += WB * 256) {
            if (e < 129024) {
                // wofrag[mc(2)][kp(9)][ks(2)][mt(7)][lane(64)][j(8)]
                const int j    = e & 7;
                const int lane = (e >> 3) & 63;
                const int mrest = e >> 9;
                const int mt = mrest % 7;
                const int q2 = mrest / 7;
                const int ks = q2 & 1;
                const int q3 = q2 >> 1;
                const int kp = q3 % 9;
                const int mc = q3 / 9;
                const int co = mc * K1M + mt * 16 + (lane & 15);
                const int ci = ks * 32 + (lane >> 4) * 8 + j;
                float v = (co < COFF) ? w_off[(size_t)co * 576 + ci * 9 + kp] : 0.f;
                wofrag[e] = f2bf(v);
            } else {
                // wfrag[ks(18)][mt(4)][lane(64)][j(8)], permuted K = g*72+kk*8+cg
                const int e2   = e - 129024;
                const int j    = e2 & 7;
                const int lane = (e2 >> 3) & 63;
                const int mt   = (e2 >> 9) & 3;
                const int ks   = e2 >> 11;
                const int m = mt * 16 + (lane & 15);
                const int k = ks * 32 + (lane >> 4) * 8 + j;
                const int g = k / 72, r = k % 72;
                const int kk = r >> 3, cg = r & 7;
                const int ci = g * 8 + cg;
                wfrag[e2] = f2bf(w_dcn[((size_t)m * CINc + ci) * 9 + kk]);
            }
        }
    }
}

// ---------- Kernel 1: 3x3 conv, waves split over M (A loaded once/block) ----
// block: 256 thr (4 waves), pixel tile 16x8 (N=128), M=112 per block (mc split).
// wave wv owns m-tiles {wv*2, wv*2+1} (wave 3: only mt 6); all 8 pixel rows.
// sigmoid fused for mask channels (co >= 144); plane output layout.
__global__ __launch_bounds__(256, 3)
void offset_conv_mfma(const unsigned short* __restrict__ featT,
                      const unsigned short* __restrict__ wofrag,
                      const float* __restrict__ b_off,
                      unsigned short* __restrict__ conv_out) {
    __shared__ unsigned short halo[10 * 18 * 72];   // [ry][rx][ci pad 72] 25920 B

    const int b  = blockIdx.z & 3;
    const int mc = blockIdx.z >> 2;
    const int h0 = blockIdx.y * 8;
    const int w0 = blockIdx.x * 16;
    const int t  = threadIdx.x;

    for (int task = t; task < 1440; task += 256) {
        const int pix = task >> 3, ch = task & 7;
        const int ry = pix / 18, rx = pix % 18;
        const int gh = h0 - 1 + ry, gw = w0 - 1 + rx;
        float4 v = make_float4(0.f, 0.f, 0.f, 0.f);
        if (gh >= 0 && gh < Hh && gw >= 0 && gw < Ww)
            v = *(const float4*)(featT + ((((size_t)b * Hh) + gh) * Ww + gw) * CINc + ch * 8);
        *(float4*)(halo + pix * 72 + ch * 8) = v;
    }
    __syncthreads();

    const int wv   = t >> 6;
    const int lane = t & 63;
    const int n    = lane & 15;
    const int kg   = lane >> 4;
    const int mt0  = wv * 2;
    const int nmt  = (wv < 3) ? 2 : 1;

    f32x4 acc[2][8] = {};

    #pragma unroll 2
    for (int s = 0; s < 18; ++s) {
        const int kp = s >> 1, ks = s & 1;
        const int ky = kp / 3, kx = kp % 3;
        const int koff = ks * 32 + kg * 8;

        // A: each wave loads only its own m-tiles (no cross-wave redundancy)
        bf16x8 af[2];
        #pragma unroll
        for (int mi = 0; mi < 2; ++mi)
            if (mi < nmt)
                af[mi] = *(const bf16x8*)(wofrag +
                    ((size_t)((((mc * 9 + kp) * 2 + ks) * 7) + mt0 + mi) * 64 + lane) * 8);

        // B: all 8 pixel rows from LDS halo
        #pragma unroll
        for (int nf = 0; nf < 8; ++nf) {
            const bf16x8 bfr = *(const bf16x8*)(halo + ((nf + ky) * 18 + (n + kx)) * 72 + koff);
            acc[0][nf] = __builtin_amdgcn_mfma_f32_16x16x32_bf16(af[0], bfr, acc[0][nf], 0, 0, 0);
            if (nmt > 1)
                acc[1][nf] = __builtin_amdgcn_mfma_f32_16x16x32_bf16(af[1], bfr, acc[1][nf], 0, 0, 0);
        }
    }

    // epilogue: C/D col=lane&15 (pixel w), row=(lane>>4)*4+r (co); plane writes
    #pragma unroll
    for (int mi = 0; mi < 2; ++mi) {
        if (mi >= nmt) break;
        #pragma unroll
        for (int nf = 0; nf < 8; ++nf) {
            const int h = h0 + nf, w = w0 + n;
            const int p = h * Ww + w;
            #pragma unroll
            for (int r = 0; r < 4; ++r) {
                const int co = mc * K1M + (mt0 + mi) * 16 + kg * 4 + r;
                if (co < COFF) {
                    float v = acc[mi][nf][r] + b_off[co];
                    if (co >= 144) v = 1.f / (1.f + expf(-v));   // fused sigmoid
                    conv_out[(((size_t)b * COFF + co) * HW) + p] = f2bf(v);
                }
            }
        }
    }
}

// ---------- Kernel 2: modulated deformable conv (MFMA GEMM) ----------------
#define K2_TW 8
#define K2_TH 4
#define TPIX 32
#define VROW 584   // 576 + 8 pad

__global__ __launch_bounds__(256, 4)
void dcn_kernel(const unsigned short* __restrict__ xG,
                const unsigned short* __restrict__ conv_out,
                const unsigned short* __restrict__ wfrag,
                const float* __restrict__ b_dcn,
                float* __restrict__ out) {
    __shared__ unsigned short vbuf[TPIX * VROW];   // 37376 B

    const int b  = blockIdx.z;
    const int h0 = blockIdx.y * K2_TH;
    const int w0 = blockIdx.x * K2_TW;
    const int t  = threadIdx.x;

    // Phase 1: bilinear sampling -> vbuf (bf16), permuted K = g*72 + kk*8 + cg
    #pragma unroll 3
    for (int it = 0; it < 9; ++it) {
        const int task = t + it * 256;
        const int pix = task & 31;
        const int q   = task >> 5;          // [0,72) = g*9 + k
        const int g   = q / 9;
        const int k   = q % 9;
        const int h = h0 + (pix >> 3);
        const int w = w0 + (pix & 7);
        const size_t obase = (((size_t)b * COFF + g * 18 + k * 2) * HW) + h * Ww + w;
        const float dy = bf2f(conv_out[obase]);
        const float dx = bf2f(conv_out[obase + HW]);
        const float mask = bf2f(conv_out[(((size_t)b * COFF + 144 + g * 9 + k) * HW) + h * Ww + w]);

        const float py  = (float)h + (float)(k / 3 - 1) + dy;
        const float pxx = (float)w + (float)(k % 3 - 1) + dx;
        const float y0f = floorf(py), x0f = floorf(pxx);
        const float ly = py - y0f, lx = pxx - x0f;
        const int y0 = (int)y0f, x0i = (int)x0f;
        const int y1 = y0 + 1,  x1  = x0i + 1;

        const float vy0 = (y0 >= 0 && y0 < Hh) ? 1.f : 0.f;
        const float vy1 = (y1 >= 0 && y1 < Hh) ? 1.f : 0.f;
        const float vx0 = (x0i >= 0 && x0i < Ww) ? 1.f : 0.f;
        const float vx1 = (x1 >= 0 && x1 < Ww) ? 1.f : 0.f;

        const float c00 = (1.f - ly) * (1.f - lx) * vy0 * vx0 * mask;
        const float c01 = (1.f - ly) * lx         * vy0 * vx1 * mask;
        const float c10 = ly         * (1.f - lx) * vy1 * vx0 * mask;
        const float c11 = ly         * lx         * vy1 * vx1 * mask;

        const int y0c = min(max(y0, 0), Hh - 1), y1c = min(max(y1, 0), Hh - 1);
        const int x0c = min(max(x0i, 0), Ww - 1), x1c = min(max(x1, 0), Ww - 1);

        const unsigned short* xb = xG + ((size_t)b * Gg + g) * HW * 8;
        const uint4 q00 = *(const uint4*)(xb + ((size_t)y0c * Ww + x0c) * 8);
        const uint4 q01 = *(const uint4*)(xb + ((size_t)y0c * Ww + x1c) * 8);
        const uint4 q10 = *(const uint4*)(xb + ((size_t)y1c * Ww + x0c) * 8);
        const uint4 q11 = *(const uint4*)(xb + ((size_t)y1c * Ww + x1c) * 8);
        const unsigned int a00[4] = {q00.x, q00.y, q00.z, q00.w};
        const unsigned int a01[4] = {q01.x, q01.y, q01.z, q01.w};
        const unsigned int a10[4] = {q10.x, q10.y, q10.z, q10.w};
        const unsigned int a11[4] = {q11.x, q11.y, q11.z, q11.w};

        unsigned short res[8];
        #pragma unroll
        for (int j = 0; j < 4; ++j) {
            const float vl = c00 * blo(a00[j]) + c01 * blo(a01[j])
                           + c10 * blo(a10[j]) + c11 * blo(a11[j]);
            const float vh = c00 * bhi(a00[j]) + c01 * bhi(a01[j])
                           + c10 * bhi(a10[j]) + c11 * bhi(a11[j]);
            res[2 * j]     = f2bf(vl);
            res[2 * j + 1] = f2bf(vh);
        }
        *(uint4*)(vbuf + (size_t)pix * VROW + g * 72 + k * 8) = *(const uint4*)res;
    }
    __syncthreads();

    // Phase 2: MFMA GEMM  out[64, 32pix] = W[64,576] * vbuf[576, 32]
    const int wv    = t >> 6;
    const int lane  = t & 63;
    const int nlane = lane & 15;
    const int kg    = lane >> 4;
    const int n0    = (wv & 1) * 16;
    const int mh    = (wv >> 1) * 2;

    f32x4 acc[2] = {};
    const unsigned short* vrow = vbuf + (size_t)(n0 + nlane) * VROW;
    #pragma unroll 6
    for (int ks = 0; ks < 18; ++ks) {
        const bf16x8 bfr = *(const bf16x8*)(vrow + ks * 32 + kg * 8);
        #pragma unroll
        for (int m = 0; m < 2; ++m) {
            const bf16x8 afr = *(const bf16x8*)(wfrag + (((size_t)ks * 4 + mh + m) * 64 + lane) * 8);
            acc[m] = __builtin_amdgcn_mfma_f32_16x16x32_bf16(afr, bfr, acc[m], 0, 0, 0);
        }
    }

    const int pix = n0 + nlane;
    const int h = h0 + (pix >> 3);
    const int w = w0 + (pix & 7);
    #pragma unroll
    for (int m = 0; m < 2; ++m) {
        const int mt = mh + m;
        #pragma unroll
        for (int r = 0; r < 4; ++r) {
            const int o = mt * 16 + kg * 4 + r;
            out[(((size_t)b * CINc + o) * HW) + h * Ww + w] = acc[m][r] + b_dcn[o];
        }
    }
}

extern "C" void kernel_launch(void* const* d_in, const int* in_sizes, int n_in,
                              void* d_out, int out_size, void* d_ws, size_t ws_size,
                              hipStream_t stream) {
    const float* x     = (const float*)d_in[0];
    const float* feat  = (const float*)d_in[1];
    const float* w_off = (const float*)d_in[2];
    const float* b_off = (const float*)d_in[3];
    const float* w_dcn = (const float*)d_in[4];
    const float* b_dcn = (const float*)d_in[5];
    float* out = (float*)d_out;

    // ws layout (ushort elements):
    unsigned short* conv_out = (unsigned short*)d_ws;              // 22,118,400
    unsigned short* featT    = conv_out + (size_t)Bn * COFF * HW;  // 6,553,600
    unsigned short* xG       = featT + (size_t)Bn * HW * CINc;     // 6,553,600
    unsigned short* wofrag   = xG + (size_t)Bn * HW * CINc;        // 129,024
    unsigned short* wfrag    = wofrag + (size_t)129024;            // 36,864
    // total ~70.8 MB

    prep_kernel<<<dim3(1280 + WB), 256, 0, stream>>>(
        feat, x, w_off, w_dcn, featT, xG, wofrag, wfrag);
    offset_conv_mfma<<<dim3(Ww / 16, Hh / 8, Bn * 2), 256, 0, stream>>>(
        featT, wofrag, b_off, conv_out);
    dcn_kernel<<<dim3(Ww / K2_TW, Hh / K2_TH, Bn), 256, 0, stream>>>(
        xG, conv_out, wfrag, b_dcn, out);
}

// Round 7
// 214.167 us; speedup vs baseline: 14.8447x; 1.1873x over previous
//
#include <hip/hip_runtime.h>
#include <math.h>

#define Bn   4
#define CINc 64
#define Hh   160
#define Ww   160
#define Gg   8
#define HW   (Hh * Ww)      // 25600
#define COFF 216

#define OROW 220            // offs row stride (ushorts): 110 dw, conflict-free stagger
#define VROW 200            // vbuf row stride (ushorts): 16B-aligned rows
#define OFFS_SZ (64 * OROW)         // 14080 ushorts
#define UNION_SZ 12800              // max(halo 7200, vbuf 64*200)
// total smem = 26880 ushorts = 53760 B -> 3 blocks/CU

typedef short bf16x8 __attribute__((ext_vector_type(8)));
typedef float f32x4  __attribute__((ext_vector_type(4)));

static __device__ __forceinline__ unsigned short f2bf(float f) {
    unsigned int u = __float_as_uint(f);
    u = (u + 0x7fffu + ((u >> 16) & 1u)) >> 16;
    return (unsigned short)u;
}
static __device__ __forceinline__ float bf2f(unsigned short s) {
    return __uint_as_float(((unsigned int)s) << 16);
}
static __device__ __forceinline__ float blo(unsigned int u) {
    return __uint_as_float(u << 16);
}
static __device__ __forceinline__ float bhi(unsigned int u) {
    return __uint_as_float(u & 0xffff0000u);
}

// ---------- Prep: transposes + weight repacks (1 launch) --------------------
// blocks [0,640): feat -> featT [b][pix][64] ; [640,1280): x -> xG [b][g][pix][8]
// [1280,1280+WB): grid-stride weight repacks (147456 wofrag + 36864 wfrag)
#define WB 180
__global__ __launch_bounds__(256)
void prep_kernel(const float* __restrict__ feat, const float* __restrict__ x,
                 const float* __restrict__ w_off, const float* __restrict__ w_dcn,
                 unsigned short* __restrict__ featT, unsigned short* __restrict__ xG,
                 unsigned short* __restrict__ wofrag, unsigned short* __restrict__ wfrag) {
    const int blk = blockIdx.x;
    const int t = threadIdx.x;
    if (blk < 1280) {
        __shared__ float tile[CINc][161];
        const int isx = blk >= 640;
        const int rem = isx ? blk - 640 : blk;
        const int b = rem / Hh;
        const int h = rem % Hh;
        const float* src = isx ? x : feat;
        for (int i = t; i < CINc * Ww; i += 256) {
            int ci = i / Ww, w = i % Ww;
            tile[ci][w] = src[(((size_t)b * CINc + ci) * Hh + h) * Ww + w];
        }
        __syncthreads();
        if (isx) {
            for (int i = t; i < CINc * Ww; i += 256) {
                int g = i / (Ww * 8);
                int r = i % (Ww * 8);
                int w = r >> 3, cg = r & 7;
                xG[(((size_t)b * Gg + g) * HW + h * Ww + w) * 8 + cg] = f2bf(tile[g * 8 + cg][w]);
            }
        } else {
            for (int i = t; i < CINc * Ww; i += 256) {
                int w = i / CINc, ci = i % CINc;
                featT[(((size_t)b * Hh + h) * Ww + w) * CINc + ci] = f2bf(tile[ci][w]);
            }
        }
    } else {
        for (int e = (blk - 1280) * 256 + t; e < 147456 + 36864; e += WB * 256) {
            if (e < 147456) {
                // wofrag[kp(9)][ks(2)][mt(16)][lane(64)][j(8)]
                const int j    = e & 7;
                const int lane = (e >> 3) & 63;
                const int rest = e >> 9;          // < 288
                const int mt = rest & 15;
                const int q  = rest >> 4;         // < 18
                const int ks = q & 1;
                const int kp = q >> 1;
                const int co = mt * 16 + (lane & 15);
                const int ci = ks * 32 + (lane >> 4) * 8 + j;
                float v = (co < COFF) ? w_off[(size_t)co * 576 + ci * 9 + kp] : 0.f;
                wofrag[e] = f2bf(v);
            } else {
                // wfrag[ks(18)][mt(4)][lane(64)][j(8)], permuted K = g*72+kk*8+cg
                const int e2   = e - 147456;
                const int j    = e2 & 7;
                const int lane = (e2 >> 3) & 63;
                const int mt   = (e2 >> 9) & 3;
                const int ks   = e2 >> 11;
                const int m = mt * 16 + (lane & 15);
                const int k = ks * 32 + (lane >> 4) * 8 + j;
                const int g = k / 72, r = k % 72;
                const int kk = r >> 3, cg = r & 7;
                const int ci = g * 8 + cg;
                wfrag[e2] = f2bf(w_dcn[((size_t)m * CINc + ci) * 9 + kk]);
            }
        }
    }
}

// ---------- Fused kernel: conv -> LDS offsets -> sample -> DCN GEMM ---------
// block = 8x8 pixel tile, 256 threads (4 waves). 1600 blocks.
__global__ __launch_bounds__(256, 3)
void dcnpack_fused(const unsigned short* __restrict__ featT,
                   const unsigned short* __restrict__ xG,
                   const unsigned short* __restrict__ wofrag,
                   const unsigned short* __restrict__ wfrag,
                   const float* __restrict__ b_off,
                   const float* __restrict__ b_dcn,
                   float* __restrict__ out) {
    __shared__ unsigned short smem[OFFS_SZ + UNION_SZ];
    unsigned short* offs = smem;                // [64 pix][OROW]: gk*3 + {dy,dx,mask}
    unsigned short* halo = smem + OFFS_SZ;      // [ry(10)][rx(10)][72] (conv phase)
    unsigned short* vbuf = smem + OFFS_SZ;      // [64 pix][VROW]     (dcn phase)

    const int b  = blockIdx.z;
    const int h0 = blockIdx.y * 8;
    const int w0 = blockIdx.x * 8;
    const int t  = threadIdx.x;
    const int wv   = t >> 6;
    const int lane = t & 63;
    const int n    = lane & 15;
    const int kg   = lane >> 4;

    // ---- stage halo: 100 pixels x 8 chunks of 8 bf16 ----
    for (int task = t; task < 800; task += 256) {
        const int pix = task >> 3, ch = task & 7;
        const int ry = pix / 10, rx = pix % 10;
        const int gh = h0 - 1 + ry, gw = w0 - 1 + rx;
        float4 v = make_float4(0.f, 0.f, 0.f, 0.f);
        if (gh >= 0 && gh < Hh && gw >= 0 && gw < Ww)
            v = *(const float4*)(featT + ((((size_t)b * Hh) + gh) * Ww + gw) * CINc + ch * 8);
        *(float4*)(halo + pix * 72 + ch * 8) = v;
    }
    __syncthreads();

    // ---- conv phase: M=256(pad of 216), N=64, K=576; wave owns mt = wv+4i ----
    // B base: pixel p = nt*16 + n -> py = nt*2 + (n>>3), pxl = n&7
    const int bbase0 = (((n >> 3) * 10) + (n & 7)) * 72 + kg * 8;

    f32x4 cacc[4][4] = {};   // [i(mt=wv+4i)][nt]
    #pragma unroll
    for (int s = 0; s < 18; ++s) {
        const int kp = s >> 1, ks = s & 1;
        const int ky = kp / 3, kx = kp % 3;
        bf16x8 af[4];
        #pragma unroll
        for (int i = 0; i < 4; ++i)
            af[i] = *(const bf16x8*)(wofrag +
                (((size_t)(kp * 2 + ks) * 16 + wv + 4 * i) * 64 + lane) * 8);
        #pragma unroll
        for (int nt = 0; nt < 4; ++nt) {
            const bf16x8 bfr = *(const bf16x8*)(halo + bbase0 + nt * 1440 +
                                                (ky * 10 + kx) * 72 + ks * 32);
            #pragma unroll
            for (int i = 0; i < 4; ++i)
                cacc[i][nt] = __builtin_amdgcn_mfma_f32_16x16x32_bf16(af[i], bfr, cacc[i][nt], 0, 0, 0);
        }
    }

    // ---- conv epilogue: bias (+sigmoid for mask) -> offs LDS ----
    #pragma unroll
    for (int i = 0; i < 4; ++i) {
        const int mt = wv + 4 * i;
        #pragma unroll
        for (int r = 0; r < 4; ++r) {
            const int co = mt * 16 + kg * 4 + r;
            if (co < COFF) {
                const float bias = b_off[co];
                const int ismask = (co >= 144);
                const int gk = ismask ? (co - 144) : (co >> 1);
                const int type = ismask ? 2 : (co & 1);
                #pragma unroll
                for (int nt = 0; nt < 4; ++nt) {
                    const int p = nt * 16 + n;
                    float v = cacc[i][nt][r] + bias;
                    if (ismask) v = 1.f / (1.f + expf(-v));
                    offs[p * OROW + gk * 3 + type] = f2bf(v);
                }
            }
        }
    }
    __syncthreads();

    // ---- DCN: 3 K-windows of 192 (24 (g,k)-units); sample -> GEMM ----
    f32x4 dacc[4] = {};   // nt; wave owns m-tile wv (o = wv*16 + kg*4 + r)

    for (int c = 0; c < 3; ++c) {
        // sampling: 64 pix x 24 units = 1536 tasks, 6/thread
        #pragma unroll 3
        for (int it = 0; it < 6; ++it) {
            const int task = t + it * 256;
            const int p    = task & 63;
            const int u    = c * 24 + (task >> 6);   // [0,72) global unit = g*9+k
            const int g    = u / 9;
            const int k    = u % 9;
            const int h = h0 + (p >> 3);
            const int w = w0 + (p & 7);

            const float dy   = bf2f(offs[p * OROW + u * 3 + 0]);
            const float dx   = bf2f(offs[p * OROW + u * 3 + 1]);
            const float mask = bf2f(offs[p * OROW + u * 3 + 2]);

            const float py  = (float)h + (float)(k / 3 - 1) + dy;
            const float pxx = (float)w + (float)(k % 3 - 1) + dx;
            const float y0f = floorf(py), x0f = floorf(pxx);
            const float ly = py - y0f, lx = pxx - x0f;
            const int y0 = (int)y0f, x0i = (int)x0f;
            const int y1 = y0 + 1,  x1  = x0i + 1;

            const float vy0 = (y0 >= 0 && y0 < Hh) ? 1.f : 0.f;
            const float vy1 = (y1 >= 0 && y1 < Hh) ? 1.f : 0.f;
            const float vx0 = (x0i >= 0 && x0i < Ww) ? 1.f : 0.f;
            const float vx1 = (x1 >= 0 && x1 < Ww) ? 1.f : 0.f;

            const float c00 = (1.f - ly) * (1.f - lx) * vy0 * vx0 * mask;
            const float c01 = (1.f - ly) * lx         * vy0 * vx1 * mask;
            const float c10 = ly         * (1.f - lx) * vy1 * vx0 * mask;
            const float c11 = ly         * lx         * vy1 * vx1 * mask;

            const int y0c = min(max(y0, 0), Hh - 1), y1c = min(max(y1, 0), Hh - 1);
            const int x0c = min(max(x0i, 0), Ww - 1), x1c = min(max(x1, 0), Ww - 1);

            const unsigned short* xb = xG + ((size_t)b * Gg + g) * HW * 8;
            const uint4 q00 = *(const uint4*)(xb + ((size_t)y0c * Ww + x0c) * 8);
            const uint4 q01 = *(const uint4*)(xb + ((size_t)y0c * Ww + x1c) * 8);
            const uint4 q10 = *(const uint4*)(xb + ((size_t)y1c * Ww + x0c) * 8);
            const uint4 q11 = *(const uint4*)(xb + ((size_t)y1c * Ww + x1c) * 8);
            const unsigned int a00[4] = {q00.x, q00.y, q00.z, q00.w};
            const unsigned int a01[4] = {q01.x, q01.y, q01.z, q01.w};
            const unsigned int a10[4] = {q10.x, q10.y, q10.z, q10.w};
            const unsigned int a11[4] = {q11.x, q11.y, q11.z, q11.w};

            unsigned short res[8];
            #pragma unroll
            for (int j = 0; j < 4; ++j) {
                const float vl = c00 * blo(a00[j]) + c01 * blo(a01[j])
                               + c10 * blo(a10[j]) + c11 * blo(a11[j]);
                const float vh = c00 * bhi(a00[j]) + c01 * bhi(a01[j])
                               + c10 * bhi(a10[j]) + c11 * bhi(a11[j]);
                res[2 * j]     = f2bf(vl);
                res[2 * j + 1] = f2bf(vh);
            }
            // k_window = (u - c*24)*8 + cg (cg contiguous) -> one 16B write
            *(uint4*)(vbuf + (size_t)p * VROW + (u - c * 24) * 8) = *(const uint4*)res;
        }
        __syncthreads();

        // GEMM over this window: 6 k-steps
        #pragma unroll
        for (int s = 0; s < 6; ++s) {
            const int ksg = c * 6 + s;
            const bf16x8 afr = *(const bf16x8*)(wfrag + (((size_t)ksg * 4 + wv) * 64 + lane) * 8);
            #pragma unroll
            for (int nt = 0; nt < 4; ++nt) {
                const bf16x8 bfr = *(const bf16x8*)(vbuf + (nt * 16 + n) * VROW + s * 32 + kg * 8);
                dacc[nt] = __builtin_amdgcn_mfma_f32_16x16x32_bf16(afr, bfr, dacc[nt], 0, 0, 0);
            }
        }
        __syncthreads();
    }

    // ---- final epilogue: C/D col=lane&15 (pixel-in-ntile), row=kg*4+r (o) ----
    #pragma unroll
    for (int nt = 0; nt < 4; ++nt) {
        const int p = nt * 16 + n;
        const int h = h0 + (p >> 3);
        const int w = w0 + (p & 7);
        #pragma unroll
        for (int r = 0; r < 4; ++r) {
            const int o = wv * 16 + kg * 4 + r;
            out[(((size_t)b * CINc + o) * HW) + h * Ww + w] = dacc[nt][r] + b_dcn[o];
        }
    }
}

extern "C" void kernel_launch(void* const* d_in, const int* in_sizes, int n_in,
                              void* d_out, int out_size, void* d_ws, size_t ws_size,
                              hipStream_t stream) {
    const float* x     = (const float*)d_in[0];
    const float* feat  = (const float*)d_in[1];
    const float* w_off = (const float*)d_in[2];
    const float* b_off = (const float*)d_in[3];
    const float* w_dcn = (const float*)d_in[4];
    const float* b_dcn = (const float*)d_in[5];
    float* out = (float*)d_out;

    // ws layout (ushort elements): featT, xG, wofrag, wfrag  (~26.6 MB)
    unsigned short* featT  = (unsigned short*)d_ws;                // 6,553,600
    unsigned short* xG     = featT + (size_t)Bn * HW * CINc;       // 6,553,600
    unsigned short* wofrag = xG + (size_t)Bn * HW * CINc;          // 147,456
    unsigned short* wfrag  = wofrag + (size_t)147456;              // 36,864

    prep_kernel<<<dim3(1280 + WB), 256, 0, stream>>>(
        feat, x, w_off, w_dcn, featT, xG, wofrag, wfrag);
    dcnpack_fused<<<dim3(Ww / 8, Hh / 8, Bn), 256, 0, stream>>>(
        featT, xG, wofrag, wfrag, b_off, b_dcn, out);
}